// Round 4
// baseline (1080.297 us; speedup 1.0000x reference)
//
#include <hip/hip_runtime.h>

// GCN 3-layer: N=100000, E=3200000, 128 -> 256 -> 256 -> 40
// Round 3: fuse aggregation+GEMM per 128-row CSR bucket (gather -> LDS bf16
// tile -> MFMA, W streamed from L2 in fragment-contiguous layout). 2-term
// hi/lo MFMA (A rounded to bf16, W kept hi+lo). Layer-3 tail in bf16.

#define NN   100000
#define NE   3200000
#define FIN  128
#define FH   256
#define FOUT 40
#define EPSV 1e-5f

#define BSH   7
#define NBKT  ((NN + 127) >> BSH)  // 782
#define CAPB  8192
#define CHNK  8192

typedef __attribute__((ext_vector_type(8))) short bf8;
typedef __attribute__((ext_vector_type(4))) float f32x4;

__device__ __forceinline__ unsigned short f2bf(float x) {
    unsigned int u = __float_as_uint(x);
    unsigned int r = u + 0x7fffu + ((u >> 16) & 1u);
    return (unsigned short)(r >> 16);
}
__device__ __forceinline__ float bf2f(unsigned short h) {
    return __uint_as_float(((unsigned int)h) << 16);
}
__device__ __forceinline__ void f2bf2(float x, unsigned short& hi, unsigned short& lo) {
    unsigned short h = f2bf(x);
    hi = h;
    lo = f2bf(x - bf2f(h));
}
__device__ __forceinline__ void acc2(unsigned int u, float& a0, float& a1) {
    a0 += __uint_as_float(u << 16);
    a1 += __uint_as_float(u & 0xffff0000u);
}

// ---- edge dtype detect ----
__global__ void k_detect(const int* __restrict__ ei, int* __restrict__ flag) {
    if (threadIdx.x == 0 && blockIdx.x == 0) {
        int z = 0;
        for (int i = 0; i < 64; i++) z |= ei[2 * i + 1];
        *flag = (z == 0) ? 1 : 0;
    }
}

// ---- pass 1: bin edges by dst>>7 into fixed-slot staging ----
__global__ __launch_bounds__(256) void k_bin(const int* __restrict__ ei,
                                             const int* __restrict__ flag,
                                             int* __restrict__ gcur,
                                             unsigned int* __restrict__ staging) {
    __shared__ int hcnt[NBKT];
    __shared__ int hbase[NBKT];
    const int tid = threadIdx.x;
    const int e0 = blockIdx.x * CHNK;
    const int f = *flag;
    for (int b = tid; b < NBKT; b += 256) hcnt[b] = 0;
    __syncthreads();
    for (int r = 0; r < CHNK / 256; r++) {
        int e = e0 + r * 256 + tid;
        if (e < NE) {
            int d = f ? ei[2 * (NE + e)] : ei[NE + e];
            atomicAdd(&hcnt[d >> BSH], 1);
        }
    }
    __syncthreads();
    for (int b = tid; b < NBKT; b += 256) {
        int c = hcnt[b];
        hbase[b] = c ? atomicAdd(&gcur[b], c) : 0;
    }
    __syncthreads();
    for (int b = tid; b < NBKT; b += 256) hcnt[b] = 0;
    __syncthreads();
    for (int r = 0; r < CHNK / 256; r++) {
        int e = e0 + r * 256 + tid;
        if (e < NE) {
            int s = f ? ei[2 * e] : ei[e];
            int d = f ? ei[2 * (NE + e)] : ei[NE + e];
            int b = d >> BSH;
            int loc = atomicAdd(&hcnt[b], 1);
            int pos = hbase[b] + loc;
            if (pos < CAPB)
                staging[(size_t)b * CAPB + pos] =
                    (unsigned int)s | ((unsigned int)(d & 127) << 17);
        }
    }
}

__global__ void k_bucketscan(const int* __restrict__ gcur, int* __restrict__ bbase) {
    __shared__ int sb[2][256];
    int t = threadIdx.x;
    int base = t * 4;
    int v0 = (base + 0 < NBKT) ? gcur[base + 0] : 0;
    int v1 = (base + 1 < NBKT) ? gcur[base + 1] : 0;
    int v2 = (base + 2 < NBKT) ? gcur[base + 2] : 0;
    int v3 = (base + 3 < NBKT) ? gcur[base + 3] : 0;
    int s0 = v0, s1 = s0 + v1, s2 = s1 + v2, s3 = s2 + v3;
    sb[0][t] = s3;
    __syncthreads();
    int pi = 0;
    for (int off = 1; off < 256; off <<= 1) {
        int x = sb[pi][t];
        if (t >= off) x += sb[pi][t - off];
        sb[pi ^ 1][t] = x;
        __syncthreads();
        pi ^= 1;
    }
    int excl = sb[pi][t] - s3;
    if (base + 0 < NBKT) bbase[base + 0] = excl;
    if (base + 1 < NBKT) bbase[base + 1] = excl + s0;
    if (base + 2 < NBKT) bbase[base + 2] = excl + s1;
    if (base + 3 < NBKT) bbase[base + 3] = excl + s2;
}

// ---- pass 2: per-bucket build of cnt/dinv/rowptr/csr ----
__global__ __launch_bounds__(256) void k_build(const unsigned int* __restrict__ staging,
                                               const int* __restrict__ gcur,
                                               const int* __restrict__ bbase,
                                               int* __restrict__ cntg,
                                               float* __restrict__ dinv,
                                               int* __restrict__ rowptr,
                                               int* __restrict__ csr) {
    __shared__ int lcnt[128];
    __shared__ int lscan[2][128];
    __shared__ int lcur[128];
    const int tid = threadIdx.x;
    const int b = blockIdx.x;
    const int tot = min(gcur[b], CAPB);
    const int bb = bbase[b];
    const unsigned int* st = staging + (size_t)b * CAPB;
    if (tid < 128) lcnt[tid] = 0;
    __syncthreads();
    for (int i = tid; i < tot; i += 256) {
        unsigned int v = st[i];
        atomicAdd(&lcnt[v >> 17], 1);
    }
    __syncthreads();
    int pi = 0;
    if (tid < 128) lscan[0][tid] = lcnt[tid];
    __syncthreads();
    for (int off = 1; off < 128; off <<= 1) {
        if (tid < 128) {
            int x = lscan[pi][tid];
            if (tid >= off) x += lscan[pi][tid - off];
            lscan[pi ^ 1][tid] = x;
        }
        __syncthreads();
        pi ^= 1;
    }
    if (tid < 128) {
        int c = lcnt[tid];
        int excl = lscan[pi][tid] - c;
        lcur[tid] = excl;
        int node = (b << BSH) + tid;
        if (node < NN) {
            cntg[node] = c;
            dinv[node] = rsqrtf((float)(c + 1));
            rowptr[node] = bb + excl;
        }
    }
    __syncthreads();
    for (int i = tid; i < tot; i += 256) {
        unsigned int v = st[i];
        int pos = atomicAdd(&lcur[v >> 17], 1);
        csr[bb + pos] = (int)(v & 0x1ffffu);
    }
}

// ---- weight prep: W[K][M] fp32 -> fragment-contiguous hi/lo bf16 ----
// layout: Wt[((k>>5)*MP + m)*32 + (k&31)]
template <int K, int M, int MP>
__global__ void k_wprep(const float* __restrict__ W, unsigned short* __restrict__ Wth,
                        unsigned short* __restrict__ Wtl) {
    int idx = blockIdx.x * blockDim.x + threadIdx.x;
    if (idx >= MP * K) return;
    int m = idx / K, k = idx - m * K;
    float v = (m < M) ? W[(size_t)k * M + m] : 0.f;
    unsigned short h, l;
    f2bf2(v, h, l);
    size_t dst = ((size_t)(k >> 5) * MP + m) * 32 + (k & 31);
    Wth[dst] = h;
    Wtl[dst] = l;
}

// ---- z * dinv -> bf16 table ----
__global__ void k_zpb(const float* __restrict__ z, const float* __restrict__ dinv,
                      unsigned short* __restrict__ zp) {
    int i = blockIdx.x * blockDim.x + threadIdx.x;
    if (i >= NN * (FIN / 2)) return;
    int row = i / (FIN / 2);
    float2 v = ((const float2*)z)[i];
    float d = dinv[row];
    unsigned int u = (unsigned int)f2bf(v.x * d) | ((unsigned int)f2bf(v.y * d) << 16);
    ((unsigned int*)zp)[i] = u;
}

// ---- fused aggregate + GEMM per 128-row bucket ----
// table[NN][K] bf16 (dinv-prescaled); out = (dinv.*(self+gather)) @ (Wh+Wl) + bias
// writes hi/lo bf16 + fused column stats. 512 thr / 8 waves; wave w owns cols
// [w*32, w*32+32). LDS A tile 128 x K bf16 (+8 pad).
template <int K>
__global__ __launch_bounds__(512, 4) void k_fused(
    const unsigned short* __restrict__ table, const float* __restrict__ dinv,
    const int* __restrict__ rowptr, const int* __restrict__ cnt,
    const int* __restrict__ csr,
    const unsigned short* __restrict__ Wth, const unsigned short* __restrict__ Wtl,
    const float* __restrict__ bias,
    unsigned short* __restrict__ outH, unsigned short* __restrict__ outL,
    float* __restrict__ s1, float* __restrict__ s2) {
    __shared__ unsigned short sA[128][K + 8];
    const int t = threadIdx.x;
    const int w = t >> 6, lane = t & 63;
    const int rowBase = blockIdx.x << 7;
    constexpr int V = K / 64;
    const int off = lane * V;

    // ---- phase 1: aggregate 16 rows per wave into LDS ----
    for (int it = 0; it < 16; it++) {
        int rloc = w * 16 + it;
        int row = rowBase + rloc;
        float acc[V];
#pragma unroll
        for (int v = 0; v < V; v++) acc[v] = 0.f;
        if (row < NN) {
            const unsigned short* xr = table + (size_t)row * K + off;
            if constexpr (V == 4) {
                uint2 u = *(const uint2*)xr;
                acc2(u.x, acc[0], acc[1]);
                acc2(u.y, acc[2], acc[3]);
            } else {
                unsigned int u = *(const unsigned int*)xr;
                acc2(u, acc[0], acc[1]);
            }
            const int rp = rowptr[row];
            const int cn = cnt[row];
            int e = 0;
            for (; e + 4 <= cn; e += 4) {
                int i0 = csr[rp + e + 0];
                int i1 = csr[rp + e + 1];
                int i2 = csr[rp + e + 2];
                int i3 = csr[rp + e + 3];
                if constexpr (V == 4) {
                    uint2 u0 = *(const uint2*)(table + (size_t)i0 * K + off);
                    uint2 u1 = *(const uint2*)(table + (size_t)i1 * K + off);
                    uint2 u2 = *(const uint2*)(table + (size_t)i2 * K + off);
                    uint2 u3 = *(const uint2*)(table + (size_t)i3 * K + off);
                    acc2(u0.x, acc[0], acc[1]); acc2(u0.y, acc[2], acc[3]);
                    acc2(u1.x, acc[0], acc[1]); acc2(u1.y, acc[2], acc[3]);
                    acc2(u2.x, acc[0], acc[1]); acc2(u2.y, acc[2], acc[3]);
                    acc2(u3.x, acc[0], acc[1]); acc2(u3.y, acc[2], acc[3]);
                } else {
                    unsigned int u0 = *(const unsigned int*)(table + (size_t)i0 * K + off);
                    unsigned int u1 = *(const unsigned int*)(table + (size_t)i1 * K + off);
                    unsigned int u2 = *(const unsigned int*)(table + (size_t)i2 * K + off);
                    unsigned int u3 = *(const unsigned int*)(table + (size_t)i3 * K + off);
                    acc2(u0, acc[0], acc[1]);
                    acc2(u1, acc[0], acc[1]);
                    acc2(u2, acc[0], acc[1]);
                    acc2(u3, acc[0], acc[1]);
                }
            }
            for (; e < cn; e++) {
                int i0 = csr[rp + e];
                if constexpr (V == 4) {
                    uint2 u0 = *(const uint2*)(table + (size_t)i0 * K + off);
                    acc2(u0.x, acc[0], acc[1]);
                    acc2(u0.y, acc[2], acc[3]);
                } else {
                    unsigned int u0 = *(const unsigned int*)(table + (size_t)i0 * K + off);
                    acc2(u0, acc[0], acc[1]);
                }
            }
            float d = dinv[row];
#pragma unroll
            for (int v = 0; v < V; v++) acc[v] *= d;
        }
        if constexpr (V == 4) {
            uint2 u;
            u.x = (unsigned int)f2bf(acc[0]) | ((unsigned int)f2bf(acc[1]) << 16);
            u.y = (unsigned int)f2bf(acc[2]) | ((unsigned int)f2bf(acc[3]) << 16);
            *(uint2*)&sA[rloc][off] = u;
        } else {
            *(unsigned int*)&sA[rloc][off] =
                (unsigned int)f2bf(acc[0]) | ((unsigned int)f2bf(acc[1]) << 16);
        }
    }
    __syncthreads();

    // ---- phase 2: GEMM from LDS, W streamed from L2 ----
    const int quad = lane >> 4, l16 = lane & 15;
    const int colW = w * 32;
    f32x4 acc[8][2];
#pragma unroll
    for (int i = 0; i < 8; i++)
#pragma unroll
        for (int j = 0; j < 2; j++) acc[i][j] = (f32x4)0.f;

    for (int k0 = 0; k0 < K; k0 += 32) {
        const int kb = k0 >> 5;
        bf8 bh[2], bl[2];
#pragma unroll
        for (int j = 0; j < 2; j++) {
            size_t bo = ((size_t)(kb * 256 + colW + j * 16 + l16)) * 32 + quad * 8;
            bh[j] = *(const bf8*)(Wth + bo);
            bl[j] = *(const bf8*)(Wtl + bo);
        }
#pragma unroll
        for (int i = 0; i < 8; i++) {
            bf8 a = *(const bf8*)&sA[i * 16 + l16][k0 + quad * 8];
#pragma unroll
            for (int j = 0; j < 2; j++) {
                acc[i][j] = __builtin_amdgcn_mfma_f32_16x16x32_bf16(a, bh[j], acc[i][j], 0, 0, 0);
                acc[i][j] = __builtin_amdgcn_mfma_f32_16x16x32_bf16(a, bl[j], acc[i][j], 0, 0, 0);
            }
        }
    }

    // ---- epilogue: bias + stats + hi/lo store ----
#pragma unroll
    for (int j = 0; j < 2; j++) {
        int col = colW + j * 16 + l16;
        float b = bias[col];
        float s1p = 0.f, s2p = 0.f;
#pragma unroll
        for (int i = 0; i < 8; i++) {
#pragma unroll
            for (int r = 0; r < 4; r++) {
                int row = rowBase + i * 16 + quad * 4 + r;
                if (row < NN) {
                    float v = acc[i][j][r] + b;
                    s1p += v;
                    s2p += v * v;
                    unsigned short h, l;
                    f2bf2(v, h, l);
                    outH[(size_t)row * 256 + col] = h;
                    outL[(size_t)row * 256 + col] = l;
                }
            }
        }
        s1p += __shfl_xor(s1p, 16); s1p += __shfl_xor(s1p, 32);
        s2p += __shfl_xor(s2p, 16); s2p += __shfl_xor(s2p, 32);
        if (quad == 0) {
            atomicAdd(&s1[col], s1p);
            atomicAdd(&s2[col], s2p);
        }
    }
}

// ---- layer-3 GEMM: H3b[NN][40] bf16 = y2[NN][256] @ (W3h+W3l) (M pad 64) ----
__global__ __launch_bounds__(256) void k_mgemm3(const unsigned short* __restrict__ y2,
                                                const unsigned short* __restrict__ Wth,
                                                const unsigned short* __restrict__ Wtl,
                                                unsigned short* __restrict__ H3b) {
    __shared__ unsigned short sA[128][40];
    const int t = threadIdx.x;
    const int w = t >> 6, lane = t & 63;
    const int quad = lane >> 4, l16 = lane & 15;
    const int rowBase = blockIdx.x << 7;
    f32x4 acc[8];
#pragma unroll
    for (int i = 0; i < 8; i++) acc[i] = (f32x4)0.f;

    for (int k0 = 0; k0 < 256; k0 += 32) {
        const int kb = k0 >> 5;
#pragma unroll
        for (int c = 0; c < 2; c++) {
            int id = t + c * 256;
            int row = id >> 2, q = id & 3;
            int gr = rowBase + row;
            int4 z = {0, 0, 0, 0};
            int4 v = (gr < NN) ? *(const int4*)(y2 + (size_t)gr * 256 + k0 + q * 8) : z;
            *(int4*)&sA[row][q * 8] = v;
        }
        __syncthreads();
        size_t bo = ((size_t)(kb * 64 + w * 16 + l16)) * 32 + quad * 8;
        bf8 bh = *(const bf8*)(Wth + bo);
        bf8 bl = *(const bf8*)(Wtl + bo);
#pragma unroll
        for (int i = 0; i < 8; i++) {
            bf8 a = *(const bf8*)&sA[i * 16 + l16][quad * 8];
            acc[i] = __builtin_amdgcn_mfma_f32_16x16x32_bf16(a, bh, acc[i], 0, 0, 0);
            acc[i] = __builtin_amdgcn_mfma_f32_16x16x32_bf16(a, bl, acc[i], 0, 0, 0);
        }
        __syncthreads();
    }
    int col = w * 16 + l16;
    if (col < FOUT) {
#pragma unroll
        for (int i = 0; i < 8; i++) {
#pragma unroll
            for (int r = 0; r < 4; r++) {
                int row = rowBase + i * 16 + quad * 4 + r;
                if (row < NN) H3b[(size_t)row * FOUT + col] = f2bf(acc[i][r]);
            }
        }
    }
}

// ---- final aggregation from bf16 H3b ----
__global__ void k_aggfb(const unsigned short* __restrict__ xp, const float* __restrict__ dinv,
                        const int* __restrict__ rowptr, const int* __restrict__ cnt,
                        const int* __restrict__ csr, const float* __restrict__ bias,
                        float* __restrict__ out) {
    const int F = FOUT;
    const int wid = threadIdx.x >> 6;
    const int lane = threadIdx.x & 63;
    const int wstep = (blockDim.x >> 6) * gridDim.x;
    const bool act = lane < F;
    for (int row = blockIdx.x * (blockDim.x >> 6) + wid; row < NN; row += wstep) {
        float acc = 0.f;
        if (act) acc = bf2f(xp[(size_t)row * F + lane]);
        const int rp = rowptr[row];
        const int cn = cnt[row];
        int e = 0;
        for (; e + 4 <= cn; e += 4) {
            int i0 = csr[rp + e + 0];
            int i1 = csr[rp + e + 1];
            int i2 = csr[rp + e + 2];
            int i3 = csr[rp + e + 3];
            if (act) {
                acc += bf2f(xp[(size_t)i0 * F + lane]) + bf2f(xp[(size_t)i1 * F + lane]) +
                       bf2f(xp[(size_t)i2 * F + lane]) + bf2f(xp[(size_t)i3 * F + lane]);
            }
        }
        for (; e < cn; e++) {
            int i0 = csr[rp + e];
            if (act) acc += bf2f(xp[(size_t)i0 * F + lane]);
        }
        if (act) out[(size_t)row * F + lane] = acc * dinv[row] + bias[lane];
    }
}

__global__ void k_bnfold(const float* __restrict__ s1, const float* __restrict__ s2,
                         const float* __restrict__ g, const float* __restrict__ be,
                         float* __restrict__ scale, float* __restrict__ shift) {
    int c = threadIdx.x;
    if (c < 256) {
        float mean = s1[c] * (1.f / NN);
        float var = s2[c] * (1.f / NN) - mean * mean;
        float sc = g[c] * rsqrtf(var + EPSV);
        scale[c] = sc;
        shift[c] = be[c] - mean * sc;
    }
}

// ---- BN+ReLU from hi/lo bf16 -> dinv-prescaled bf16 table ----
__global__ void k_bnr(const unsigned short* __restrict__ xh, const unsigned short* __restrict__ xl,
                      const float* __restrict__ scale, const float* __restrict__ shift,
                      const float* __restrict__ dinv, unsigned short* __restrict__ oh) {
    int i = blockIdx.x * blockDim.x + threadIdx.x;
    if (i >= NN * 128) return;
    int row = i >> 7;
    int c = (i & 127) * 2;
    unsigned int uh = ((const unsigned int*)xh)[i];
    unsigned int ul = ((const unsigned int*)xl)[i];
    float x0 = __uint_as_float(uh << 16) + __uint_as_float(ul << 16);
    float x1 = __uint_as_float(uh & 0xffff0000u) + __uint_as_float(ul & 0xffff0000u);
    float d = dinv[row];
    float v0 = fmaxf(x0 * scale[c + 0] + shift[c + 0], 0.f) * d;
    float v1 = fmaxf(x1 * scale[c + 1] + shift[c + 1], 0.f) * d;
    ((unsigned int*)oh)[i] = (unsigned int)f2bf(v0) | ((unsigned int)f2bf(v1) << 16);
}

extern "C" void kernel_launch(void* const* d_in, const int* in_sizes, int n_in,
                              void* d_out, int out_size, void* d_ws, size_t ws_size,
                              hipStream_t stream) {
    const int* ei = (const int*)d_in[0];
    const float* z = (const float*)d_in[1];
    const float* W1 = (const float*)d_in[2];
    const float* b1 = (const float*)d_in[3];
    const float* g1 = (const float*)d_in[4];
    const float* be1 = (const float*)d_in[5];
    const float* W2 = (const float*)d_in[6];
    const float* b2 = (const float*)d_in[7];
    const float* g2 = (const float*)d_in[8];
    const float* be2 = (const float*)d_in[9];
    const float* W3 = (const float*)d_in[10];
    const float* b3 = (const float*)d_in[11];
    float* out = (float*)d_out;

    char* w = (char*)d_ws;
    size_t o = 0;
    auto take = [&](size_t bytes) {
        char* p = w + o;
        o = (o + bytes + 255) & ~(size_t)255;
        return p;
    };
    int* cnt = (int*)take((size_t)NN * 4);
    int* rowptr = (int*)take((size_t)NN * 4);
    int* gcur = (int*)take(NBKT * 4);
    int* bbase = (int*)take(NBKT * 4);
    int* iflag = (int*)take(4);
    int* csr = (int*)take((size_t)NE * 4);
    unsigned int* staging = (unsigned int*)take((size_t)NBKT * CAPB * 4);
    float* dinv = (float*)take((size_t)NN * 4);
    float* stat = (float*)take(4 * 256 * 4);
    float* sc1 = (float*)take(256 * 4);
    float* sh1 = (float*)take(256 * 4);
    float* sc2 = (float*)take(256 * 4);
    float* sh2 = (float*)take(256 * 4);
    unsigned short* Wt1h = (unsigned short*)take(256 * 128 * 2);
    unsigned short* Wt1l = (unsigned short*)take(256 * 128 * 2);
    unsigned short* Wt2h = (unsigned short*)take(256 * 256 * 2);
    unsigned short* Wt2l = (unsigned short*)take(256 * 256 * 2);
    unsigned short* Wt3h = (unsigned short*)take(64 * 256 * 2);
    unsigned short* Wt3l = (unsigned short*)take(64 * 256 * 2);
    unsigned short* P1 = (unsigned short*)take((size_t)NN * 256 * 2);   // 51.2 MB
    unsigned short* P2 = (unsigned short*)take((size_t)NN * 512 * 2);   // 102.4 MB

    unsigned short* zp = P1;                       // N x 128 (dead after fused1)
    unsigned short* x1h = P2;                      // N x 256
    unsigned short* x1l = P2 + (size_t)NN * 256;
    unsigned short* y1 = P1;                       // N x 256 (overlay zp)
    unsigned short* x2h = P2;                      // overlay x1
    unsigned short* x2l = P2 + (size_t)NN * 256;
    unsigned short* y2 = P1;                       // overlay y1
    unsigned short* H3b = P2;                      // N x 40 bf16 (overlay x2)
    float* s1a = stat, *s2a = stat + 256, *s1b = stat + 512, *s2b = stat + 768;

    hipMemsetAsync(gcur, 0, NBKT * 4, stream);
    hipMemsetAsync(stat, 0, 4 * 256 * 4, stream);

    // CSR build
    k_detect<<<1, 1, 0, stream>>>(ei, iflag);
    k_bin<<<(NE + CHNK - 1) / CHNK, 256, 0, stream>>>(ei, iflag, gcur, staging);
    k_bucketscan<<<1, 256, 0, stream>>>(gcur, bbase);
    k_build<<<NBKT, 256, 0, stream>>>(staging, gcur, bbase, cnt, dinv, rowptr, csr);

    k_wprep<128, 256, 256><<<(256 * 128 + 255) / 256, 256, 0, stream>>>(W1, Wt1h, Wt1l);
    k_wprep<256, 256, 256><<<(256 * 256 + 255) / 256, 256, 0, stream>>>(W2, Wt2h, Wt2l);
    k_wprep<256, 40, 64><<<(64 * 256 + 255) / 256, 256, 0, stream>>>(W3, Wt3h, Wt3l);

    // layer 1 (fused agg + GEMM)
    k_zpb<<<(NN * 64 + 255) / 256, 256, 0, stream>>>(z, dinv, zp);
    k_fused<128><<<NBKT, 512, 0, stream>>>(zp, dinv, rowptr, cnt, csr, Wt1h, Wt1l, b1,
                                           x1h, x1l, s1a, s2a);
    k_bnfold<<<1, 256, 0, stream>>>(s1a, s2a, g1, be1, sc1, sh1);
    k_bnr<<<(NN * 128 + 255) / 256, 256, 0, stream>>>(x1h, x1l, sc1, sh1, dinv, y1);

    // layer 2 (fused agg + GEMM)
    k_fused<256><<<NBKT, 512, 0, stream>>>(y1, dinv, rowptr, cnt, csr, Wt2h, Wt2l, b2,
                                           x2h, x2l, s1b, s2b);
    k_bnfold<<<1, 256, 0, stream>>>(s1b, s2b, g2, be2, sc2, sh2);
    k_bnr<<<(NN * 128 + 255) / 256, 256, 0, stream>>>(x2h, x2l, sc2, sh2, dinv, y2);

    // layer 3
    k_mgemm3<<<NBKT, 256, 0, stream>>>(y2, Wt3h, Wt3l, H3b);
    k_aggfb<<<2560, 256, 0, stream>>>(H3b, dinv, rowptr, cnt, csr, b3, out);
}

// Round 5
// 967.405 us; speedup vs baseline: 1.1167x; 1.1167x over previous
//
#include <hip/hip_runtime.h>

// GCN 3-layer: N=100000, E=3200000, 128 -> 256 -> 256 -> 40
// Round 5: UNFUSE (occupancy beats fusion for random gathers — r4 lesson).
// Single-bf16 activations/A-tiles everywhere; W hi/lo 2-term MFMA.
// aggb: VGPR-lean grid-stride gather (70% occ, ~3.5 TB/s fabric).
// gemm: 64x128 tile, 256 thr, 32 acc regs/wave -> 32 waves/CU, W from L2.

#define NN   100000
#define NE   3200000
#define FIN  128
#define FH   256
#define FOUT 40
#define EPSV 1e-5f

#define BSH   7
#define NBKT  ((NN + 127) >> BSH)  // 782
#define CAPB  8192
#define CHNK  8192

typedef __attribute__((ext_vector_type(8))) short bf8;
typedef __attribute__((ext_vector_type(4))) float f32x4;

__device__ __forceinline__ unsigned short f2bf(float x) {
    unsigned int u = __float_as_uint(x);
    unsigned int r = u + 0x7fffu + ((u >> 16) & 1u);
    return (unsigned short)(r >> 16);
}
__device__ __forceinline__ float bf2f(unsigned short h) {
    return __uint_as_float(((unsigned int)h) << 16);
}
__device__ __forceinline__ void f2bf2(float x, unsigned short& hi, unsigned short& lo) {
    unsigned short h = f2bf(x);
    hi = h;
    lo = f2bf(x - bf2f(h));
}
__device__ __forceinline__ void acc2(unsigned int u, float& a0, float& a1) {
    a0 += __uint_as_float(u << 16);
    a1 += __uint_as_float(u & 0xffff0000u);
}

// ---- edge dtype detect ----
__global__ void k_detect(const int* __restrict__ ei, int* __restrict__ flag) {
    if (threadIdx.x == 0 && blockIdx.x == 0) {
        int z = 0;
        for (int i = 0; i < 64; i++) z |= ei[2 * i + 1];
        *flag = (z == 0) ? 1 : 0;
    }
}

// ---- pass 1: bin edges by dst>>7 into fixed-slot staging ----
__global__ __launch_bounds__(256) void k_bin(const int* __restrict__ ei,
                                             const int* __restrict__ flag,
                                             int* __restrict__ gcur,
                                             unsigned int* __restrict__ staging) {
    __shared__ int hcnt[NBKT];
    __shared__ int hbase[NBKT];
    const int tid = threadIdx.x;
    const int e0 = blockIdx.x * CHNK;
    const int f = *flag;
    for (int b = tid; b < NBKT; b += 256) hcnt[b] = 0;
    __syncthreads();
    for (int r = 0; r < CHNK / 256; r++) {
        int e = e0 + r * 256 + tid;
        if (e < NE) {
            int d = f ? ei[2 * (NE + e)] : ei[NE + e];
            atomicAdd(&hcnt[d >> BSH], 1);
        }
    }
    __syncthreads();
    for (int b = tid; b < NBKT; b += 256) {
        int c = hcnt[b];
        hbase[b] = c ? atomicAdd(&gcur[b], c) : 0;
    }
    __syncthreads();
    for (int b = tid; b < NBKT; b += 256) hcnt[b] = 0;
    __syncthreads();
    for (int r = 0; r < CHNK / 256; r++) {
        int e = e0 + r * 256 + tid;
        if (e < NE) {
            int s = f ? ei[2 * e] : ei[e];
            int d = f ? ei[2 * (NE + e)] : ei[NE + e];
            int b = d >> BSH;
            int loc = atomicAdd(&hcnt[b], 1);
            int pos = hbase[b] + loc;
            if (pos < CAPB)
                staging[(size_t)b * CAPB + pos] =
                    (unsigned int)s | ((unsigned int)(d & 127) << 17);
        }
    }
}

__global__ void k_bucketscan(const int* __restrict__ gcur, int* __restrict__ bbase) {
    __shared__ int sb[2][256];
    int t = threadIdx.x;
    int base = t * 4;
    int v0 = (base + 0 < NBKT) ? gcur[base + 0] : 0;
    int v1 = (base + 1 < NBKT) ? gcur[base + 1] : 0;
    int v2 = (base + 2 < NBKT) ? gcur[base + 2] : 0;
    int v3 = (base + 3 < NBKT) ? gcur[base + 3] : 0;
    int s0 = v0, s1 = s0 + v1, s2 = s1 + v2, s3 = s2 + v3;
    sb[0][t] = s3;
    __syncthreads();
    int pi = 0;
    for (int off = 1; off < 256; off <<= 1) {
        int x = sb[pi][t];
        if (t >= off) x += sb[pi][t - off];
        sb[pi ^ 1][t] = x;
        __syncthreads();
        pi ^= 1;
    }
    int excl = sb[pi][t] - s3;
    if (base + 0 < NBKT) bbase[base + 0] = excl;
    if (base + 1 < NBKT) bbase[base + 1] = excl + s0;
    if (base + 2 < NBKT) bbase[base + 2] = excl + s1;
    if (base + 3 < NBKT) bbase[base + 3] = excl + s2;
}

// ---- pass 2: per-bucket build of cnt/dinv/rowptr/csr ----
__global__ __launch_bounds__(256) void k_build(const unsigned int* __restrict__ staging,
                                               const int* __restrict__ gcur,
                                               const int* __restrict__ bbase,
                                               int* __restrict__ cntg,
                                               float* __restrict__ dinv,
                                               int* __restrict__ rowptr,
                                               int* __restrict__ csr) {
    __shared__ int lcnt[128];
    __shared__ int lscan[2][128];
    __shared__ int lcur[128];
    const int tid = threadIdx.x;
    const int b = blockIdx.x;
    const int tot = min(gcur[b], CAPB);
    const int bb = bbase[b];
    const unsigned int* st = staging + (size_t)b * CAPB;
    if (tid < 128) lcnt[tid] = 0;
    __syncthreads();
    for (int i = tid; i < tot; i += 256) {
        unsigned int v = st[i];
        atomicAdd(&lcnt[v >> 17], 1);
    }
    __syncthreads();
    int pi = 0;
    if (tid < 128) lscan[0][tid] = lcnt[tid];
    __syncthreads();
    for (int off = 1; off < 128; off <<= 1) {
        if (tid < 128) {
            int x = lscan[pi][tid];
            if (tid >= off) x += lscan[pi][tid - off];
            lscan[pi ^ 1][tid] = x;
        }
        __syncthreads();
        pi ^= 1;
    }
    if (tid < 128) {
        int c = lcnt[tid];
        int excl = lscan[pi][tid] - c;
        lcur[tid] = excl;
        int node = (b << BSH) + tid;
        if (node < NN) {
            cntg[node] = c;
            dinv[node] = rsqrtf((float)(c + 1));
            rowptr[node] = bb + excl;
        }
    }
    __syncthreads();
    for (int i = tid; i < tot; i += 256) {
        unsigned int v = st[i];
        int pos = atomicAdd(&lcur[v >> 17], 1);
        csr[bb + pos] = (int)(v & 0x1ffffu);
    }
}

// ---- weight prep: W[K][M] fp32 -> fragment-contiguous hi/lo bf16 ----
// layout: Wt[((k>>5)*MP + m)*32 + (k&31)]
template <int K, int M, int MP>
__global__ void k_wprep(const float* __restrict__ W, unsigned short* __restrict__ Wth,
                        unsigned short* __restrict__ Wtl) {
    int idx = blockIdx.x * blockDim.x + threadIdx.x;
    if (idx >= MP * K) return;
    int m = idx / K, k = idx - m * K;
    float v = (m < M) ? W[(size_t)k * M + m] : 0.f;
    unsigned short h, l;
    f2bf2(v, h, l);
    size_t dst = ((size_t)(k >> 5) * MP + m) * 32 + (k & 31);
    Wth[dst] = h;
    Wtl[dst] = l;
}

// ---- z * dinv -> bf16 table ----
__global__ void k_zpb(const float* __restrict__ z, const float* __restrict__ dinv,
                      unsigned short* __restrict__ zp) {
    int i = blockIdx.x * blockDim.x + threadIdx.x;
    if (i >= NN * (FIN / 2)) return;
    int row = i / (FIN / 2);
    float2 v = ((const float2*)z)[i];
    float d = dinv[row];
    unsigned int u = (unsigned int)f2bf(v.x * d) | ((unsigned int)f2bf(v.y * d) << 16);
    ((unsigned int*)zp)[i] = u;
}

// ---- bf16 gather aggregation -> single bf16 out (x dinv), unroll 8 ----
template <int F, int V>
__global__ void k_aggb(const unsigned short* __restrict__ xp, const float* __restrict__ dinv,
                       const int* __restrict__ rowptr, const int* __restrict__ cnt,
                       const int* __restrict__ csr, unsigned short* __restrict__ oa) {
    const int wid = threadIdx.x >> 6;
    const int lane = threadIdx.x & 63;
    const int wstep = (blockDim.x >> 6) * gridDim.x;
    const int off = lane * V;
    for (int row = blockIdx.x * (blockDim.x >> 6) + wid; row < NN; row += wstep) {
        float acc[V];
#pragma unroll
        for (int v = 0; v < V; v++) acc[v] = 0.f;
        {
            const unsigned short* xr = xp + (size_t)row * F + off;
            if constexpr (V == 4) {
                uint2 u = *(const uint2*)xr;
                acc2(u.x, acc[0], acc[1]);
                acc2(u.y, acc[2], acc[3]);
            } else {
                unsigned int u = *(const unsigned int*)xr;
                acc2(u, acc[0], acc[1]);
            }
        }
        const int rp = rowptr[row];
        const int cn = cnt[row];
        int e = 0;
        for (; e + 8 <= cn; e += 8) {
            int idx[8];
#pragma unroll
            for (int q = 0; q < 8; q++) idx[q] = csr[rp + e + q];
            if constexpr (V == 4) {
                uint2 u[8];
#pragma unroll
                for (int q = 0; q < 8; q++) u[q] = *(const uint2*)(xp + (size_t)idx[q] * F + off);
#pragma unroll
                for (int q = 0; q < 8; q++) {
                    acc2(u[q].x, acc[0], acc[1]);
                    acc2(u[q].y, acc[2], acc[3]);
                }
            } else {
                unsigned int u[8];
#pragma unroll
                for (int q = 0; q < 8; q++) u[q] = *(const unsigned int*)(xp + (size_t)idx[q] * F + off);
#pragma unroll
                for (int q = 0; q < 8; q++) acc2(u[q], acc[0], acc[1]);
            }
        }
        for (; e < cn; e++) {
            int i0 = csr[rp + e];
            if constexpr (V == 4) {
                uint2 u0 = *(const uint2*)(xp + (size_t)i0 * F + off);
                acc2(u0.x, acc[0], acc[1]);
                acc2(u0.y, acc[2], acc[3]);
            } else {
                unsigned int u0 = *(const unsigned int*)(xp + (size_t)i0 * F + off);
                acc2(u0, acc[0], acc[1]);
            }
        }
        float d = dinv[row];
        size_t p = (size_t)row * F + off;
        if constexpr (V == 4) {
            uint2 u;
            u.x = (unsigned int)f2bf(acc[0] * d) | ((unsigned int)f2bf(acc[1] * d) << 16);
            u.y = (unsigned int)f2bf(acc[2] * d) | ((unsigned int)f2bf(acc[3] * d) << 16);
            *(uint2*)(oa + p) = u;
        } else {
            *(unsigned int*)(oa + p) =
                (unsigned int)f2bf(acc[0] * d) | ((unsigned int)f2bf(acc[1] * d) << 16);
        }
    }
}

// ---- GEMM: x[64-row tile][128-col tile] = A[.,K]bf16 @ (Wh+Wl) + bias; stats fused ----
// grid (2, ceil(NN/64)); 256 thr = 4 waves, wave w owns cols colBase + w*32.
template <int K>
__global__ __launch_bounds__(256) void k_gemm(const unsigned short* __restrict__ A,
                                              const unsigned short* __restrict__ Wth,
                                              const unsigned short* __restrict__ Wtl,
                                              const float* __restrict__ bias,
                                              unsigned short* __restrict__ outX,
                                              float* __restrict__ s1,
                                              float* __restrict__ s2) {
    __shared__ unsigned short sA[64][40];
    const int t = threadIdx.x;
    const int w = t >> 6, lane = t & 63;
    const int quad = lane >> 4, l16 = lane & 15;
    const int rowBase = blockIdx.y * 64;
    const int colW = blockIdx.x * 128 + w * 32;
    f32x4 acc[4][2];
#pragma unroll
    for (int i = 0; i < 4; i++)
#pragma unroll
        for (int j = 0; j < 2; j++) acc[i][j] = (f32x4)0.f;

    for (int k0 = 0; k0 < K; k0 += 32) {
        int gr = rowBase + (t >> 2);
        int4 v = {0, 0, 0, 0};
        if (gr < NN) v = *(const int4*)(A + (size_t)gr * K + k0 + (t & 3) * 8);
        __syncthreads();
        *(int4*)&sA[t >> 2][(t & 3) * 8] = v;
        __syncthreads();
        const int kb = k0 >> 5;
        bf8 bh[2], bl[2];
#pragma unroll
        for (int j = 0; j < 2; j++) {
            size_t bo = ((size_t)(kb * 256 + colW + j * 16 + l16)) * 32 + quad * 8;
            bh[j] = *(const bf8*)(Wth + bo);
            bl[j] = *(const bf8*)(Wtl + bo);
        }
#pragma unroll
        for (int i = 0; i < 4; i++) {
            bf8 a = *(const bf8*)&sA[i * 16 + l16][quad * 8];
#pragma unroll
            for (int j = 0; j < 2; j++) {
                acc[i][j] = __builtin_amdgcn_mfma_f32_16x16x32_bf16(a, bh[j], acc[i][j], 0, 0, 0);
                acc[i][j] = __builtin_amdgcn_mfma_f32_16x16x32_bf16(a, bl[j], acc[i][j], 0, 0, 0);
            }
        }
    }
#pragma unroll
    for (int j = 0; j < 2; j++) {
        int col = colW + j * 16 + l16;
        float b = bias[col];
        float s1p = 0.f, s2p = 0.f;
#pragma unroll
        for (int i = 0; i < 4; i++) {
#pragma unroll
            for (int r = 0; r < 4; r++) {
                int row = rowBase + i * 16 + quad * 4 + r;
                if (row < NN) {
                    float v = acc[i][j][r] + b;
                    s1p += v;
                    s2p += v * v;
                    outX[(size_t)row * 256 + col] = f2bf(v);
                }
            }
        }
        s1p += __shfl_xor(s1p, 16); s1p += __shfl_xor(s1p, 32);
        s2p += __shfl_xor(s2p, 16); s2p += __shfl_xor(s2p, 32);
        if (quad == 0) {
            atomicAdd(&s1[col], s1p);
            atomicAdd(&s2[col], s2p);
        }
    }
}

// ---- layer-3 GEMM: H3b[NN][40] bf16 = y2[NN][256] @ (W3h+W3l) (M pad 64) ----
__global__ __launch_bounds__(256) void k_mgemm3(const unsigned short* __restrict__ y2,
                                                const unsigned short* __restrict__ Wth,
                                                const unsigned short* __restrict__ Wtl,
                                                unsigned short* __restrict__ H3b) {
    __shared__ unsigned short sA[128][40];
    const int t = threadIdx.x;
    const int w = t >> 6, lane = t & 63;
    const int quad = lane >> 4, l16 = lane & 15;
    const int rowBase = blockIdx.x << 7;
    f32x4 acc[8];
#pragma unroll
    for (int i = 0; i < 8; i++) acc[i] = (f32x4)0.f;

    for (int k0 = 0; k0 < 256; k0 += 32) {
        const int kb = k0 >> 5;
#pragma unroll
        for (int c = 0; c < 2; c++) {
            int id = t + c * 256;
            int row = id >> 2, q = id & 3;
            int gr = rowBase + row;
            int4 z = {0, 0, 0, 0};
            int4 v = (gr < NN) ? *(const int4*)(y2 + (size_t)gr * 256 + k0 + q * 8) : z;
            __syncthreads();
            *(int4*)&sA[row][q * 8] = v;
        }
        __syncthreads();
        size_t bo = ((size_t)(kb * 64 + w * 16 + l16)) * 32 + quad * 8;
        bf8 bh = *(const bf8*)(Wth + bo);
        bf8 bl = *(const bf8*)(Wtl + bo);
#pragma unroll
        for (int i = 0; i < 8; i++) {
            bf8 a = *(const bf8*)&sA[i * 16 + l16][quad * 8];
            acc[i] = __builtin_amdgcn_mfma_f32_16x16x32_bf16(a, bh, acc[i], 0, 0, 0);
            acc[i] = __builtin_amdgcn_mfma_f32_16x16x32_bf16(a, bl, acc[i], 0, 0, 0);
        }
    }
    int col = w * 16 + l16;
    if (col < FOUT) {
#pragma unroll
        for (int i = 0; i < 8; i++) {
#pragma unroll
            for (int r = 0; r < 4; r++) {
                int row = rowBase + i * 16 + quad * 4 + r;
                if (row < NN) H3b[(size_t)row * FOUT + col] = f2bf(acc[i][r]);
            }
        }
    }
}

// ---- final aggregation from bf16 H3b ----
__global__ void k_aggfb(const unsigned short* __restrict__ xp, const float* __restrict__ dinv,
                        const int* __restrict__ rowptr, const int* __restrict__ cnt,
                        const int* __restrict__ csr, const float* __restrict__ bias,
                        float* __restrict__ out) {
    const int F = FOUT;
    const int wid = threadIdx.x >> 6;
    const int lane = threadIdx.x & 63;
    const int wstep = (blockDim.x >> 6) * gridDim.x;
    const bool act = lane < F;
    for (int row = blockIdx.x * (blockDim.x >> 6) + wid; row < NN; row += wstep) {
        float acc = 0.f;
        if (act) acc = bf2f(xp[(size_t)row * F + lane]);
        const int rp = rowptr[row];
        const int cn = cnt[row];
        int e = 0;
        for (; e + 4 <= cn; e += 4) {
            int i0 = csr[rp + e + 0];
            int i1 = csr[rp + e + 1];
            int i2 = csr[rp + e + 2];
            int i3 = csr[rp + e + 3];
            if (act) {
                acc += bf2f(xp[(size_t)i0 * F + lane]) + bf2f(xp[(size_t)i1 * F + lane]) +
                       bf2f(xp[(size_t)i2 * F + lane]) + bf2f(xp[(size_t)i3 * F + lane]);
            }
        }
        for (; e < cn; e++) {
            int i0 = csr[rp + e];
            if (act) acc += bf2f(xp[(size_t)i0 * F + lane]);
        }
        if (act) out[(size_t)row * F + lane] = acc * dinv[row] + bias[lane];
    }
}

__global__ void k_bnfold(const float* __restrict__ s1, const float* __restrict__ s2,
                         const float* __restrict__ g, const float* __restrict__ be,
                         float* __restrict__ scale, float* __restrict__ shift) {
    int c = threadIdx.x;
    if (c < 256) {
        float mean = s1[c] * (1.f / NN);
        float var = s2[c] * (1.f / NN) - mean * mean;
        float sc = g[c] * rsqrtf(var + EPSV);
        scale[c] = sc;
        shift[c] = be[c] - mean * sc;
    }
}

// ---- BN+ReLU from single bf16 x -> dinv-prescaled bf16 table ----
__global__ void k_bnr(const unsigned short* __restrict__ x,
                      const float* __restrict__ scale, const float* __restrict__ shift,
                      const float* __restrict__ dinv, unsigned short* __restrict__ oy) {
    int i = blockIdx.x * blockDim.x + threadIdx.x;
    if (i >= NN * 128) return;
    int row = i >> 7;
    int c = (i & 127) * 2;
    unsigned int u = ((const unsigned int*)x)[i];
    float x0 = __uint_as_float(u << 16);
    float x1 = __uint_as_float(u & 0xffff0000u);
    float d = dinv[row];
    float v0 = fmaxf(x0 * scale[c + 0] + shift[c + 0], 0.f) * d;
    float v1 = fmaxf(x1 * scale[c + 1] + shift[c + 1], 0.f) * d;
    ((unsigned int*)oy)[i] = (unsigned int)f2bf(v0) | ((unsigned int)f2bf(v1) << 16);
}

extern "C" void kernel_launch(void* const* d_in, const int* in_sizes, int n_in,
                              void* d_out, int out_size, void* d_ws, size_t ws_size,
                              hipStream_t stream) {
    const int* ei = (const int*)d_in[0];
    const float* z = (const float*)d_in[1];
    const float* W1 = (const float*)d_in[2];
    const float* b1 = (const float*)d_in[3];
    const float* g1 = (const float*)d_in[4];
    const float* be1 = (const float*)d_in[5];
    const float* W2 = (const float*)d_in[6];
    const float* b2 = (const float*)d_in[7];
    const float* g2 = (const float*)d_in[8];
    const float* be2 = (const float*)d_in[9];
    const float* W3 = (const float*)d_in[10];
    const float* b3 = (const float*)d_in[11];
    float* out = (float*)d_out;

    char* w = (char*)d_ws;
    size_t o = 0;
    auto take = [&](size_t bytes) {
        char* p = w + o;
        o = (o + bytes + 255) & ~(size_t)255;
        return p;
    };
    int* cnt = (int*)take((size_t)NN * 4);
    int* rowptr = (int*)take((size_t)NN * 4);
    int* gcur = (int*)take(NBKT * 4);
    int* bbase = (int*)take(NBKT * 4);
    int* iflag = (int*)take(4);
    int* csr = (int*)take((size_t)NE * 4);
    unsigned int* staging = (unsigned int*)take((size_t)NBKT * CAPB * 4);
    float* dinv = (float*)take((size_t)NN * 4);
    float* stat = (float*)take(4 * 256 * 4);
    float* sc1 = (float*)take(256 * 4);
    float* sh1 = (float*)take(256 * 4);
    float* sc2 = (float*)take(256 * 4);
    float* sh2 = (float*)take(256 * 4);
    unsigned short* Wt1h = (unsigned short*)take(256 * 128 * 2);
    unsigned short* Wt1l = (unsigned short*)take(256 * 128 * 2);
    unsigned short* Wt2h = (unsigned short*)take(256 * 256 * 2);
    unsigned short* Wt2l = (unsigned short*)take(256 * 256 * 2);
    unsigned short* Wt3h = (unsigned short*)take(64 * 256 * 2);
    unsigned short* Wt3l = (unsigned short*)take(64 * 256 * 2);
    unsigned short* P1 = (unsigned short*)take((size_t)NN * 256 * 2);   // 51.2 MB
    unsigned short* P2 = (unsigned short*)take((size_t)NN * 512 * 2);   // 102.4 MB

    unsigned short* zp = P1;                       // N x 128
    unsigned short* a1 = P1 + (size_t)NN * 128;    // N x 128
    unsigned short* x1 = P2;                       // N x 256 (first half)
    unsigned short* y1 = P1;                       // N x 256 (overlay zp+a1)
    unsigned short* a2 = P2 + (size_t)NN * 256;    // N x 256 (second half)
    unsigned short* x2 = P2;                       // overlay x1 (dead)
    unsigned short* y2 = P1;                       // overlay y1 (dead)
    unsigned short* H3b = P2 + (size_t)NN * 256;   // overlay a2 (dead)
    float* s1a = stat, *s2a = stat + 256, *s1b = stat + 512, *s2b = stat + 768;

    hipMemsetAsync(gcur, 0, NBKT * 4, stream);
    hipMemsetAsync(stat, 0, 4 * 256 * 4, stream);

    // CSR build (two-level counting sort)
    k_detect<<<1, 1, 0, stream>>>(ei, iflag);
    k_bin<<<(NE + CHNK - 1) / CHNK, 256, 0, stream>>>(ei, iflag, gcur, staging);
    k_bucketscan<<<1, 256, 0, stream>>>(gcur, bbase);
    k_build<<<NBKT, 256, 0, stream>>>(staging, gcur, bbase, cnt, dinv, rowptr, csr);

    k_wprep<128, 256, 256><<<(256 * 128 + 255) / 256, 256, 0, stream>>>(W1, Wt1h, Wt1l);
    k_wprep<256, 256, 256><<<(256 * 256 + 255) / 256, 256, 0, stream>>>(W2, Wt2h, Wt2l);
    k_wprep<256, 40, 64><<<(64 * 256 + 255) / 256, 256, 0, stream>>>(W3, Wt3h, Wt3l);

    const int GR = (NN + 63) / 64;   // 1563

    // layer 1
    k_zpb<<<(NN * 64 + 255) / 256, 256, 0, stream>>>(z, dinv, zp);
    k_aggb<128, 2><<<2560, 256, 0, stream>>>(zp, dinv, rowptr, cnt, csr, a1);
    k_gemm<128><<<dim3(2, GR), 256, 0, stream>>>(a1, Wt1h, Wt1l, b1, x1, s1a, s2a);
    k_bnfold<<<1, 256, 0, stream>>>(s1a, s2a, g1, be1, sc1, sh1);
    k_bnr<<<(NN * 128 + 255) / 256, 256, 0, stream>>>(x1, sc1, sh1, dinv, y1);

    // layer 2
    k_aggb<256, 4><<<2560, 256, 0, stream>>>(y1, dinv, rowptr, cnt, csr, a2);
    k_gemm<256><<<dim3(2, GR), 256, 0, stream>>>(a2, Wt2h, Wt2l, b2, x2, s1b, s2b);
    k_bnfold<<<1, 256, 0, stream>>>(s1b, s2b, g2, be2, sc2, sh2);
    k_bnr<<<(NN * 128 + 255) / 256, 256, 0, stream>>>(x2, sc2, sh2, dinv, y2);

    // layer 3
    k_mgemm3<<<NBKT, 256, 0, stream>>>(y2, Wt3h, Wt3l, H3b);
    k_aggfb<<<2560, 256, 0, stream>>>(H3b, dinv, rowptr, cnt, csr, b3, out);
}

// Round 6
// 867.412 us; speedup vs baseline: 1.2454x; 1.1153x over previous
//
#include <hip/hip_runtime.h>

// GCN 3-layer: N=100000, E=3200000, 128 -> 256 -> 256 -> 40
// Round 6: row-wise int8 gather tables (the gathers are fabric-BW bound at
// ~3.5 TB/s; bytes/edge is the only lever). zp: signed int8 128B rows;
// y1: unsigned int8 (post-relu) 256B rows; H3: signed int8 padded to 64 cols
// (1 cache line per gather). Per-row scales (400KB, L2-resident).
// GEMMs stay bf16-A x (Whi+Wlo) 2-term MFMA with fused BN stats.

#define NN   100000
#define NE   3200000
#define FIN  128
#define FH   256
#define FOUT 40
#define EPSV 1e-5f

#define BSH   7
#define NBKT  ((NN + 127) >> BSH)  // 782
#define CAPB  8192
#define CHNK  4096

typedef __attribute__((ext_vector_type(8))) short bf8;
typedef __attribute__((ext_vector_type(4))) float f32x4;

__device__ __forceinline__ unsigned short f2bf(float x) {
    unsigned int u = __float_as_uint(x);
    unsigned int r = u + 0x7fffu + ((u >> 16) & 1u);
    return (unsigned short)(r >> 16);
}
__device__ __forceinline__ float bf2f(unsigned short h) {
    return __uint_as_float(((unsigned int)h) << 16);
}
__device__ __forceinline__ void f2bf2(float x, unsigned short& hi, unsigned short& lo) {
    unsigned short h = f2bf(x);
    hi = h;
    lo = f2bf(x - bf2f(h));
}
__device__ __forceinline__ float ub(unsigned int u, int k) {
    return (float)((u >> (8 * k)) & 0xffu);           // -> v_cvt_f32_ubyte
}
__device__ __forceinline__ float sb(unsigned int u, int k) {
    return (float)(int)(signed char)((u >> (8 * k)) & 0xffu);
}

// ---- edge dtype detect ----
__global__ void k_detect(const int* __restrict__ ei, int* __restrict__ flag) {
    if (threadIdx.x == 0 && blockIdx.x == 0) {
        int z = 0;
        for (int i = 0; i < 64; i++) z |= ei[2 * i + 1];
        *flag = (z == 0) ? 1 : 0;
    }
}

// ---- pass 1: bin edges by dst>>7 into fixed-slot staging ----
__global__ __launch_bounds__(256) void k_bin(const int* __restrict__ ei,
                                             const int* __restrict__ flag,
                                             int* __restrict__ gcur,
                                             unsigned int* __restrict__ staging) {
    __shared__ int hcnt[NBKT];
    __shared__ int hbase[NBKT];
    const int tid = threadIdx.x;
    const int e0 = blockIdx.x * CHNK;
    const int f = *flag;
    for (int b = tid; b < NBKT; b += 256) hcnt[b] = 0;
    __syncthreads();
    for (int r = 0; r < CHNK / 256; r++) {
        int e = e0 + r * 256 + tid;
        if (e < NE) {
            int d = f ? ei[2 * (NE + e)] : ei[NE + e];
            atomicAdd(&hcnt[d >> BSH], 1);
        }
    }
    __syncthreads();
    for (int b = tid; b < NBKT; b += 256) {
        int c = hcnt[b];
        hbase[b] = c ? atomicAdd(&gcur[b], c) : 0;
    }
    __syncthreads();
    for (int b = tid; b < NBKT; b += 256) hcnt[b] = 0;
    __syncthreads();
    for (int r = 0; r < CHNK / 256; r++) {
        int e = e0 + r * 256 + tid;
        if (e < NE) {
            int s = f ? ei[2 * e] : ei[e];
            int d = f ? ei[2 * (NE + e)] : ei[NE + e];
            int b = d >> BSH;
            int loc = atomicAdd(&hcnt[b], 1);
            int pos = hbase[b] + loc;
            if (pos < CAPB)
                staging[(size_t)b * CAPB + pos] =
                    (unsigned int)s | ((unsigned int)(d & 127) << 17);
        }
    }
}

__global__ void k_bucketscan(const int* __restrict__ gcur, int* __restrict__ bbase) {
    __shared__ int sb2[2][256];
    int t = threadIdx.x;
    int base = t * 4;
    int v0 = (base + 0 < NBKT) ? gcur[base + 0] : 0;
    int v1 = (base + 1 < NBKT) ? gcur[base + 1] : 0;
    int v2 = (base + 2 < NBKT) ? gcur[base + 2] : 0;
    int v3 = (base + 3 < NBKT) ? gcur[base + 3] : 0;
    int s0 = v0, s1 = s0 + v1, s2 = s1 + v2, s3 = s2 + v3;
    sb2[0][t] = s3;
    __syncthreads();
    int pi = 0;
    for (int off = 1; off < 256; off <<= 1) {
        int x = sb2[pi][t];
        if (t >= off) x += sb2[pi][t - off];
        sb2[pi ^ 1][t] = x;
        __syncthreads();
        pi ^= 1;
    }
    int excl = sb2[pi][t] - s3;
    if (base + 0 < NBKT) bbase[base + 0] = excl;
    if (base + 1 < NBKT) bbase[base + 1] = excl + s0;
    if (base + 2 < NBKT) bbase[base + 2] = excl + s1;
    if (base + 3 < NBKT) bbase[base + 3] = excl + s2;
}

// ---- pass 2: per-bucket build of cnt/dinv/rowptr/csr ----
__global__ __launch_bounds__(256) void k_build(const unsigned int* __restrict__ staging,
                                               const int* __restrict__ gcur,
                                               const int* __restrict__ bbase,
                                               int* __restrict__ cntg,
                                               float* __restrict__ dinv,
                                               int* __restrict__ rowptr,
                                               int* __restrict__ csr) {
    __shared__ int lcnt[128];
    __shared__ int lscan[2][128];
    __shared__ int lcur[128];
    const int tid = threadIdx.x;
    const int b = blockIdx.x;
    const int tot = min(gcur[b], CAPB);
    const int bb = bbase[b];
    const unsigned int* st = staging + (size_t)b * CAPB;
    if (tid < 128) lcnt[tid] = 0;
    __syncthreads();
    for (int i = tid; i < tot; i += 256) {
        unsigned int v = st[i];
        atomicAdd(&lcnt[v >> 17], 1);
    }
    __syncthreads();
    int pi = 0;
    if (tid < 128) lscan[0][tid] = lcnt[tid];
    __syncthreads();
    for (int off = 1; off < 128; off <<= 1) {
        if (tid < 128) {
            int x = lscan[pi][tid];
            if (tid >= off) x += lscan[pi][tid - off];
            lscan[pi ^ 1][tid] = x;
        }
        __syncthreads();
        pi ^= 1;
    }
    if (tid < 128) {
        int c = lcnt[tid];
        int excl = lscan[pi][tid] - c;
        lcur[tid] = excl;
        int node = (b << BSH) + tid;
        if (node < NN) {
            cntg[node] = c;
            dinv[node] = rsqrtf((float)(c + 1));
            rowptr[node] = bb + excl;
        }
    }
    __syncthreads();
    for (int i = tid; i < tot; i += 256) {
        unsigned int v = st[i];
        int pos = atomicAdd(&lcur[v >> 17], 1);
        csr[bb + pos] = (int)(v & 0x1ffffu);
    }
}

// ---- weight prep: W[K][M] fp32 -> fragment-contiguous hi/lo bf16 ----
template <int K, int M, int MP>
__global__ void k_wprep(const float* __restrict__ W, unsigned short* __restrict__ Wth,
                        unsigned short* __restrict__ Wtl) {
    int idx = blockIdx.x * blockDim.x + threadIdx.x;
    if (idx >= MP * K) return;
    int m = idx / K, k = idx - m * K;
    float v = (m < M) ? W[(size_t)k * M + m] : 0.f;
    unsigned short h, l;
    f2bf2(v, h, l);
    size_t dst = ((size_t)(k >> 5) * MP + m) * 32 + (k & 31);
    Wth[dst] = h;
    Wtl[dst] = l;
}

// ---- z * dinv -> signed int8 rows + per-row scale (wave per row) ----
__global__ __launch_bounds__(256) void k_zpb8(const float* __restrict__ z,
                                              const float* __restrict__ dinv,
                                              unsigned char* __restrict__ zp8,
                                              float* __restrict__ scaleZ) {
    int wv = (blockIdx.x * blockDim.x + threadIdx.x) >> 6;
    int lane = threadIdx.x & 63;
    if (wv >= NN) return;
    float2 v = *(const float2*)(z + (size_t)wv * FIN + lane * 2);
    float d = dinv[wv];
    float a0 = v.x * d, a1 = v.y * d;
    float m = fmaxf(fabsf(a0), fabsf(a1));
#pragma unroll
    for (int off = 1; off < 64; off <<= 1) m = fmaxf(m, __shfl_xor(m, off));
    float inv = m > 0.f ? 127.f / m : 0.f;
    int q0 = (int)rintf(a0 * inv), q1 = (int)rintf(a1 * inv);
    unsigned short pk = (unsigned short)((q0 & 0xff) | ((q1 & 0xff) << 8));
    *(unsigned short*)(zp8 + (size_t)wv * FIN + lane * 2) = pk;
    if (lane == 0) scaleZ[wv] = m * (1.f / 127.f);
}

// ---- BN+ReLU+dinv -> unsigned int8 rows + per-row scale (wave per row) ----
__global__ __launch_bounds__(256) void k_bnr8(const unsigned short* __restrict__ x,
                                              const float* __restrict__ scale,
                                              const float* __restrict__ shift,
                                              const float* __restrict__ dinv,
                                              unsigned char* __restrict__ y8,
                                              float* __restrict__ scaleY) {
    int wv = (blockIdx.x * blockDim.x + threadIdx.x) >> 6;
    int lane = threadIdx.x & 63;
    if (wv >= NN) return;
    uint2 u = *(const uint2*)(x + (size_t)wv * 256 + lane * 4);
    float4 sc = *(const float4*)(scale + lane * 4);
    float4 sh = *(const float4*)(shift + lane * 4);
    float d = dinv[wv];
    float v0 = fmaxf(__uint_as_float(u.x << 16) * sc.x + sh.x, 0.f) * d;
    float v1 = fmaxf(__uint_as_float(u.x & 0xffff0000u) * sc.y + sh.y, 0.f) * d;
    float v2 = fmaxf(__uint_as_float(u.y << 16) * sc.z + sh.z, 0.f) * d;
    float v3 = fmaxf(__uint_as_float(u.y & 0xffff0000u) * sc.w + sh.w, 0.f) * d;
    float m = fmaxf(fmaxf(v0, v1), fmaxf(v2, v3));
#pragma unroll
    for (int off = 1; off < 64; off <<= 1) m = fmaxf(m, __shfl_xor(m, off));
    float inv = m > 0.f ? 255.f / m : 0.f;
    unsigned int q0 = (unsigned int)(v0 * inv + 0.5f);
    unsigned int q1 = (unsigned int)(v1 * inv + 0.5f);
    unsigned int q2 = (unsigned int)(v2 * inv + 0.5f);
    unsigned int q3 = (unsigned int)(v3 * inv + 0.5f);
    *(unsigned int*)(y8 + (size_t)wv * 256 + lane * 4) = q0 | (q1 << 8) | (q2 << 16) | (q3 << 24);
    if (lane == 0) scaleY[wv] = m * (1.f / 255.f);
}

// ---- int8 gather aggregation -> bf16 out (x dinv), unroll 8 ----
// F=128: SIGNED, 2 bytes/lane; F=256: unsigned, 4 bytes/lane.
template <int F, bool SIGNED>
__global__ void k_agg8(const unsigned char* __restrict__ tab, const float* __restrict__ rscale,
                       const float* __restrict__ dinv,
                       const int* __restrict__ rowptr, const int* __restrict__ cnt,
                       const int* __restrict__ csr, unsigned short* __restrict__ oa) {
    const int wid = threadIdx.x >> 6;
    const int lane = threadIdx.x & 63;
    const int wstep = (blockDim.x >> 6) * gridDim.x;
    constexpr int B = F / 64;
    const int off = lane * B;
    for (int row = blockIdx.x * (blockDim.x >> 6) + wid; row < NN; row += wstep) {
        float acc[B];
#pragma unroll
        for (int v = 0; v < B; v++) acc[v] = 0.f;
        // self term
        {
            float s = rscale[row];
            if constexpr (B == 4) {
                unsigned int u = *(const unsigned int*)(tab + (size_t)row * F + off);
                acc[0] += s * ub(u, 0); acc[1] += s * ub(u, 1);
                acc[2] += s * ub(u, 2); acc[3] += s * ub(u, 3);
            } else {
                unsigned int u = *(const unsigned short*)(tab + (size_t)row * F + off);
                acc[0] += s * sb(u, 0); acc[1] += s * sb(u, 1);
            }
        }
        const int rp = rowptr[row];
        const int cn = cnt[row];
        int e = 0;
        for (; e + 8 <= cn; e += 8) {
            int idx[8];
            float s[8];
            unsigned int u[8];
#pragma unroll
            for (int q = 0; q < 8; q++) idx[q] = csr[rp + e + q];
#pragma unroll
            for (int q = 0; q < 8; q++) {
                s[q] = rscale[idx[q]];
                if constexpr (B == 4)
                    u[q] = *(const unsigned int*)(tab + (size_t)idx[q] * F + off);
                else
                    u[q] = *(const unsigned short*)(tab + (size_t)idx[q] * F + off);
            }
#pragma unroll
            for (int q = 0; q < 8; q++) {
                if constexpr (B == 4) {
                    acc[0] += s[q] * ub(u[q], 0); acc[1] += s[q] * ub(u[q], 1);
                    acc[2] += s[q] * ub(u[q], 2); acc[3] += s[q] * ub(u[q], 3);
                } else {
                    acc[0] += s[q] * sb(u[q], 0); acc[1] += s[q] * sb(u[q], 1);
                }
            }
        }
        for (; e < cn; e++) {
            int i0 = csr[rp + e];
            float s = rscale[i0];
            if constexpr (B == 4) {
                unsigned int u = *(const unsigned int*)(tab + (size_t)i0 * F + off);
                acc[0] += s * ub(u, 0); acc[1] += s * ub(u, 1);
                acc[2] += s * ub(u, 2); acc[3] += s * ub(u, 3);
            } else {
                unsigned int u = *(const unsigned short*)(tab + (size_t)i0 * F + off);
                acc[0] += s * sb(u, 0); acc[1] += s * sb(u, 1);
            }
        }
        float d = dinv[row];
        size_t p = (size_t)row * F + off;
        if constexpr (B == 4) {
            uint2 o;
            o.x = (unsigned int)f2bf(acc[0] * d) | ((unsigned int)f2bf(acc[1] * d) << 16);
            o.y = (unsigned int)f2bf(acc[2] * d) | ((unsigned int)f2bf(acc[3] * d) << 16);
            *(uint2*)(oa + p) = o;
        } else {
            *(unsigned int*)(oa + p) =
                (unsigned int)f2bf(acc[0] * d) | ((unsigned int)f2bf(acc[1] * d) << 16);
        }
    }
}

// ---- GEMM: 64-row x 128-col tile; A bf16, W hi/lo; bias + BN stats fused ----
template <int K>
__global__ __launch_bounds__(256) void k_gemm(const unsigned short* __restrict__ A,
                                              const unsigned short* __restrict__ Wth,
                                              const unsigned short* __restrict__ Wtl,
                                              const float* __restrict__ bias,
                                              unsigned short* __restrict__ outX,
                                              float* __restrict__ s1,
                                              float* __restrict__ s2) {
    __shared__ unsigned short sA[64][40];
    const int t = threadIdx.x;
    const int w = t >> 6, lane = t & 63;
    const int quad = lane >> 4, l16 = lane & 15;
    const int rowBase = blockIdx.y * 64;
    const int colW = blockIdx.x * 128 + w * 32;
    f32x4 acc[4][2];
#pragma unroll
    for (int i = 0; i < 4; i++)
#pragma unroll
        for (int j = 0; j < 2; j++) acc[i][j] = (f32x4)0.f;

    for (int k0 = 0; k0 < K; k0 += 32) {
        int gr = rowBase + (t >> 2);
        int4 v = {0, 0, 0, 0};
        if (gr < NN) v = *(const int4*)(A + (size_t)gr * K + k0 + (t & 3) * 8);
        __syncthreads();
        *(int4*)&sA[t >> 2][(t & 3) * 8] = v;
        __syncthreads();
        const int kb = k0 >> 5;
        bf8 bh[2], bl[2];
#pragma unroll
        for (int j = 0; j < 2; j++) {
            size_t bo = ((size_t)(kb * 256 + colW + j * 16 + l16)) * 32 + quad * 8;
            bh[j] = *(const bf8*)(Wth + bo);
            bl[j] = *(const bf8*)(Wtl + bo);
        }
#pragma unroll
        for (int i = 0; i < 4; i++) {
            bf8 a = *(const bf8*)&sA[i * 16 + l16][quad * 8];
#pragma unroll
            for (int j = 0; j < 2; j++) {
                acc[i][j] = __builtin_amdgcn_mfma_f32_16x16x32_bf16(a, bh[j], acc[i][j], 0, 0, 0);
                acc[i][j] = __builtin_amdgcn_mfma_f32_16x16x32_bf16(a, bl[j], acc[i][j], 0, 0, 0);
            }
        }
    }
#pragma unroll
    for (int j = 0; j < 2; j++) {
        int col = colW + j * 16 + l16;
        float b = bias[col];
        float s1p = 0.f, s2p = 0.f;
#pragma unroll
        for (int i = 0; i < 4; i++) {
#pragma unroll
            for (int r = 0; r < 4; r++) {
                int row = rowBase + i * 16 + quad * 4 + r;
                if (row < NN) {
                    float v = acc[i][j][r] + b;
                    s1p += v;
                    s2p += v * v;
                    outX[(size_t)row * 256 + col] = f2bf(v);
                }
            }
        }
        s1p += __shfl_xor(s1p, 16); s1p += __shfl_xor(s1p, 32);
        s2p += __shfl_xor(s2p, 16); s2p += __shfl_xor(s2p, 32);
        if (quad == 0) {
            atomicAdd(&s1[col], s1p);
            atomicAdd(&s2[col], s2p);
        }
    }
}

// ---- layer-3 GEMM: y2[NN][256] bf16 @ (W3h+W3l) -> signed int8 H3 (64-col pad)
//      + per-row scale via cross-wave row-max epilogue ----
__global__ __launch_bounds__(256) void k_mgemm3(const unsigned short* __restrict__ y2,
                                                const unsigned short* __restrict__ Wth,
                                                const unsigned short* __restrict__ Wtl,
                                                unsigned char* __restrict__ H8,
                                                float* __restrict__ scaleH) {
    __shared__ unsigned short sA[128][40];
    __shared__ float sM[128][4];
    const int t = threadIdx.x;
    const int w = t >> 6, lane = t & 63;
    const int quad = lane >> 4, l16 = lane & 15;
    const int rowBase = blockIdx.x << 7;
    f32x4 acc[8];
#pragma unroll
    for (int i = 0; i < 8; i++) acc[i] = (f32x4)0.f;

    for (int k0 = 0; k0 < 256; k0 += 32) {
        const int kb = k0 >> 5;
        int id0 = t, id1 = t + 256;
        int gr0 = rowBase + (id0 >> 2), gr1 = rowBase + (id1 >> 2);
        int4 zz = {0, 0, 0, 0};
        int4 v0 = (gr0 < NN) ? *(const int4*)(y2 + (size_t)gr0 * 256 + k0 + (id0 & 3) * 8) : zz;
        int4 v1 = (gr1 < NN) ? *(const int4*)(y2 + (size_t)gr1 * 256 + k0 + (id1 & 3) * 8) : zz;
        __syncthreads();
        *(int4*)&sA[id0 >> 2][(id0 & 3) * 8] = v0;
        *(int4*)&sA[id1 >> 2][(id1 & 3) * 8] = v1;
        __syncthreads();
        size_t bo = ((size_t)(kb * 64 + w * 16 + l16)) * 32 + quad * 8;
        bf8 bh = *(const bf8*)(Wth + bo);
        bf8 bl = *(const bf8*)(Wtl + bo);
#pragma unroll
        for (int i = 0; i < 8; i++) {
            bf8 a = *(const bf8*)&sA[i * 16 + l16][quad * 8];
            acc[i] = __builtin_amdgcn_mfma_f32_16x16x32_bf16(a, bh, acc[i], 0, 0, 0);
            acc[i] = __builtin_amdgcn_mfma_f32_16x16x32_bf16(a, bl, acc[i], 0, 0, 0);
        }
    }
    // epilogue: per-row absmax across 64 cols (16 in-wave via shfl, 4 waves via LDS)
#pragma unroll
    for (int i = 0; i < 8; i++) {
#pragma unroll
        for (int r = 0; r < 4; r++) {
            float m = fabsf(acc[i][r]);
            m = fmaxf(m, __shfl_xor(m, 1));
            m = fmaxf(m, __shfl_xor(m, 2));
            m = fmaxf(m, __shfl_xor(m, 4));
            m = fmaxf(m, __shfl_xor(m, 8));
            if (l16 == 0) sM[i * 16 + quad * 4 + r][w] = m;
        }
    }
    __syncthreads();
    const int col = w * 16 + l16;
#pragma unroll
    for (int i = 0; i < 8; i++) {
#pragma unroll
        for (int r = 0; r < 4; r++) {
            int rloc = i * 16 + quad * 4 + r;
            int row = rowBase + rloc;
            float m = fmaxf(fmaxf(sM[rloc][0], sM[rloc][1]), fmaxf(sM[rloc][2], sM[rloc][3]));
            float inv = m > 0.f ? 127.f / m : 0.f;
            if (row < NN) {
                int q = (int)rintf(acc[i][r] * inv);
                H8[(size_t)row * 64 + col] = (unsigned char)(q & 0xff);
                if (w == 0 && l16 == 0) scaleH[row] = m * (1.f / 127.f);
            }
        }
    }
}

// ---- final aggregation from int8 H8 (64B rows = 1 line/gather) ----
__global__ void k_aggfb8(const unsigned char* __restrict__ tab, const float* __restrict__ rscale,
                         const float* __restrict__ dinv,
                         const int* __restrict__ rowptr, const int* __restrict__ cnt,
                         const int* __restrict__ csr, const float* __restrict__ bias,
                         float* __restrict__ out) {
    const int wid = threadIdx.x >> 6;
    const int lane = threadIdx.x & 63;
    const int wstep = (blockDim.x >> 6) * gridDim.x;
    for (int row = blockIdx.x * (blockDim.x >> 6) + wid; row < NN; row += wstep) {
        float acc = rscale[row] * (float)(int)(signed char)tab[(size_t)row * 64 + lane];
        const int rp = rowptr[row];
        const int cn = cnt[row];
        int e = 0;
        for (; e + 4 <= cn; e += 4) {
            int i0 = csr[rp + e + 0];
            int i1 = csr[rp + e + 1];
            int i2 = csr[rp + e + 2];
            int i3 = csr[rp + e + 3];
            float s0 = rscale[i0], s1 = rscale[i1], s2 = rscale[i2], s3 = rscale[i3];
            float q0 = (float)(int)(signed char)tab[(size_t)i0 * 64 + lane];
            float q1 = (float)(int)(signed char)tab[(size_t)i1 * 64 + lane];
            float q2 = (float)(int)(signed char)tab[(size_t)i2 * 64 + lane];
            float q3 = (float)(int)(signed char)tab[(size_t)i3 * 64 + lane];
            acc += s0 * q0 + s1 * q1 + s2 * q2 + s3 * q3;
        }
        for (; e < cn; e++) {
            int i0 = csr[rp + e];
            acc += rscale[i0] * (float)(int)(signed char)tab[(size_t)i0 * 64 + lane];
        }
        if (lane < FOUT) out[(size_t)row * FOUT + lane] = acc * dinv[row] + bias[lane];
    }
}

__global__ void k_bnfold(const float* __restrict__ s1, const float* __restrict__ s2,
                         const float* __restrict__ g, const float* __restrict__ be,
                         float* __restrict__ scale, float* __restrict__ shift) {
    int c = threadIdx.x;
    if (c < 256) {
        float mean = s1[c] * (1.f / NN);
        float var = s2[c] * (1.f / NN) - mean * mean;
        float sc = g[c] * rsqrtf(var + EPSV);
        scale[c] = sc;
        shift[c] = be[c] - mean * sc;
    }
}

// ---- BN+ReLU bf16->bf16 table (x dinv) — layer-2 output for mgemm3 ----
__global__ void k_bnr(const unsigned short* __restrict__ x,
                      const float* __restrict__ scale, const float* __restrict__ shift,
                      const float* __restrict__ dinv, unsigned short* __restrict__ oy) {
    int i = blockIdx.x * blockDim.x + threadIdx.x;
    if (i >= NN * 128) return;
    int row = i >> 7;
    int c = (i & 127) * 2;
    unsigned int u = ((const unsigned int*)x)[i];
    float x0 = __uint_as_float(u << 16);
    float x1 = __uint_as_float(u & 0xffff0000u);
    float d = dinv[row];
    float v0 = fmaxf(x0 * scale[c + 0] + shift[c + 0], 0.f) * d;
    float v1 = fmaxf(x1 * scale[c + 1] + shift[c + 1], 0.f) * d;
    ((unsigned int*)oy)[i] = (unsigned int)f2bf(v0) | ((unsigned int)f2bf(v1) << 16);
}

extern "C" void kernel_launch(void* const* d_in, const int* in_sizes, int n_in,
                              void* d_out, int out_size, void* d_ws, size_t ws_size,
                              hipStream_t stream) {
    const int* ei = (const int*)d_in[0];
    const float* z = (const float*)d_in[1];
    const float* W1 = (const float*)d_in[2];
    const float* b1 = (const float*)d_in[3];
    const float* g1 = (const float*)d_in[4];
    const float* be1 = (const float*)d_in[5];
    const float* W2 = (const float*)d_in[6];
    const float* b2 = (const float*)d_in[7];
    const float* g2 = (const float*)d_in[8];
    const float* be2 = (const float*)d_in[9];
    const float* W3 = (const float*)d_in[10];
    const float* b3 = (const float*)d_in[11];
    float* out = (float*)d_out;

    char* w = (char*)d_ws;
    size_t o = 0;
    auto take = [&](size_t bytes) {
        char* p = w + o;
        o = (o + bytes + 255) & ~(size_t)255;
        return p;
    };
    int* cnt = (int*)take((size_t)NN * 4);
    int* rowptr = (int*)take((size_t)NN * 4);
    int* gcur = (int*)take(NBKT * 4);
    int* bbase = (int*)take(NBKT * 4);
    int* iflag = (int*)take(4);
    int* csr = (int*)take((size_t)NE * 4);
    unsigned int* staging = (unsigned int*)take((size_t)NBKT * CAPB * 4);   // 25.6 MB
    float* dinv = (float*)take((size_t)NN * 4);
    float* stat = (float*)take(4 * 256 * 4);
    float* sc1 = (float*)take(256 * 4);
    float* sh1 = (float*)take(256 * 4);
    float* sc2 = (float*)take(256 * 4);
    float* sh2 = (float*)take(256 * 4);
    unsigned short* Wt1h = (unsigned short*)take(256 * 128 * 2);
    unsigned short* Wt1l = (unsigned short*)take(256 * 128 * 2);
    unsigned short* Wt2h = (unsigned short*)take(256 * 256 * 2);
    unsigned short* Wt2l = (unsigned short*)take(256 * 256 * 2);
    unsigned short* Wt3h = (unsigned short*)take(64 * 256 * 2);
    unsigned short* Wt3l = (unsigned short*)take(64 * 256 * 2);
    unsigned char* zp8 = (unsigned char*)take((size_t)NN * FIN);      // 12.8 MB
    unsigned char* y1_8 = (unsigned char*)take((size_t)NN * FH);      // 25.6 MB
    unsigned char* H8 = (unsigned char*)take((size_t)NN * 64);        // 6.4 MB
    float* scaleZ = (float*)take((size_t)NN * 4);
    float* scaleY = (float*)take((size_t)NN * 4);
    float* scaleH = (float*)take((size_t)NN * 4);
    unsigned short* P1 = (unsigned short*)take((size_t)NN * 256 * 2);   // 51.2 MB
    unsigned short* P2 = (unsigned short*)take((size_t)NN * 512 * 2);   // 102.4 MB

    unsigned short* a1 = P1;                       // N x 128 bf16
    unsigned short* x1 = P2;                       // N x 256 bf16
    unsigned short* a2 = P2 + (size_t)NN * 256;    // N x 256 bf16
    unsigned short* x2 = P1;                       // N x 256 (a1 dead)
    unsigned short* y2 = P2;                       // N x 256 (x1 dead)
    float* s1a = stat, *s2a = stat + 256, *s1b = stat + 512, *s2b = stat + 768;

    hipMemsetAsync(gcur, 0, NBKT * 4, stream);
    hipMemsetAsync(stat, 0, 4 * 256 * 4, stream);

    // CSR build (two-level counting sort)
    k_detect<<<1, 1, 0, stream>>>(ei, iflag);
    k_bin<<<(NE + CHNK - 1) / CHNK, 256, 0, stream>>>(ei, iflag, gcur, staging);
    k_bucketscan<<<1, 256, 0, stream>>>(gcur, bbase);
    k_build<<<NBKT, 256, 0, stream>>>(staging, gcur, bbase, cnt, dinv, rowptr, csr);

    k_wprep<128, 256, 256><<<(256 * 128 + 255) / 256, 256, 0, stream>>>(W1, Wt1h, Wt1l);
    k_wprep<256, 256, 256><<<(256 * 256 + 255) / 256, 256, 0, stream>>>(W2, Wt2h, Wt2l);
    k_wprep<256, 40, 64><<<(64 * 256 + 255) / 256, 256, 0, stream>>>(W3, Wt3h, Wt3l);

    const int GR = (NN + 63) / 64;     // 1563
    const int WV = (NN + 3) / 4;       // wave-per-row blocks (4 waves each)

    // layer 1
    k_zpb8<<<WV, 256, 0, stream>>>(z, dinv, zp8, scaleZ);
    k_agg8<128, true><<<2560, 256, 0, stream>>>(zp8, scaleZ, dinv, rowptr, cnt, csr, a1);
    k_gemm<128><<<dim3(2, GR), 256, 0, stream>>>(a1, Wt1h, Wt1l, b1, x1, s1a, s2a);
    k_bnfold<<<1, 256, 0, stream>>>(s1a, s2a, g1, be1, sc1, sh1);
    k_bnr8<<<WV, 256, 0, stream>>>(x1, sc1, sh1, dinv, y1_8, scaleY);

    // layer 2
    k_agg8<256, false><<<2560, 256, 0, stream>>>(y1_8, scaleY, dinv, rowptr, cnt, csr, a2);
    k_gemm<256><<<dim3(2, GR), 256, 0, stream>>>(a2, Wt2h, Wt2l, b2, x2, s1b, s2b);
    k_bnfold<<<1, 256, 0, stream>>>(s1b, s2b, g2, be2, sc2, sh2);
    k_bnr<<<(NN * 128 + 255) / 256, 256, 0, stream>>>(x2, sc2, sh2, dinv, y2);

    // layer 3
    k_mgemm3<<<NBKT, 256, 0, stream>>>(y2, Wt3h, Wt3l, H8, scaleH);
    k_aggfb8<<<2560, 256, 0, stream>>>(H8, scaleH, dinv, rowptr, cnt, csr, b3, out);
}

// Round 7
// 791.500 us; speedup vs baseline: 1.3649x; 1.0959x over previous
//
#include <hip/hip_runtime.h>

// GCN 3-layer: N=100000, E=3200000, 128 -> 256 -> 256 -> 40
// Round 7: cooperative csr/rscale staging in the gather kernels — indices and
// scales are wave-uniform, so load 64 at a time across lanes and broadcast via
// __shfl (2 VMEM per 64 neighbors instead of 128; inner loop = 1 payload load
// + 2 shfl + unpack). Fold detect into k_bin; single fused wprep.
// Tables: zp signed i8 (128B rows), y1 unsigned i8 (256B), H3 signed i8 (64B).

#define NN   100000
#define NE   3200000
#define FIN  128
#define FH   256
#define FOUT 40
#define EPSV 1e-5f

#define BSH   7
#define NBKT  ((NN + 127) >> BSH)  // 782
#define CAPB  8192
#define CHNK  4096

typedef __attribute__((ext_vector_type(8))) short bf8;
typedef __attribute__((ext_vector_type(4))) float f32x4;

__device__ __forceinline__ unsigned short f2bf(float x) {
    unsigned int u = __float_as_uint(x);
    unsigned int r = u + 0x7fffu + ((u >> 16) & 1u);
    return (unsigned short)(r >> 16);
}
__device__ __forceinline__ float bf2f(unsigned short h) {
    return __uint_as_float(((unsigned int)h) << 16);
}
__device__ __forceinline__ void f2bf2(float x, unsigned short& hi, unsigned short& lo) {
    unsigned short h = f2bf(x);
    hi = h;
    lo = f2bf(x - bf2f(h));
}
__device__ __forceinline__ float ub(unsigned int u, int k) {
    return (float)((u >> (8 * k)) & 0xffu);
}
__device__ __forceinline__ float sbyte(unsigned int u, int k) {
    return (float)(int)(signed char)((u >> (8 * k)) & 0xffu);
}

// ---- pass 1: bin edges by dst>>7 into fixed-slot staging (flag computed inline) ----
__global__ __launch_bounds__(256) void k_bin(const int* __restrict__ ei,
                                             int* __restrict__ gcur,
                                             unsigned int* __restrict__ staging) {
    __shared__ int hcnt[NBKT];
    __shared__ int hbase[NBKT];
    __shared__ int sflag;
    const int tid = threadIdx.x;
    const int e0 = blockIdx.x * CHNK;
    for (int b = tid; b < NBKT; b += 256) hcnt[b] = 0;
    if (tid == 0) {
        int zz = 0;
        for (int i = 0; i < 64; i++) zz |= ei[2 * i + 1];
        sflag = (zz == 0) ? 1 : 0;
    }
    __syncthreads();
    const int f = sflag;
    for (int r = 0; r < CHNK / 256; r++) {
        int e = e0 + r * 256 + tid;
        if (e < NE) {
            int d = f ? ei[2 * (NE + e)] : ei[NE + e];
            atomicAdd(&hcnt[d >> BSH], 1);
        }
    }
    __syncthreads();
    for (int b = tid; b < NBKT; b += 256) {
        int c = hcnt[b];
        hbase[b] = c ? atomicAdd(&gcur[b], c) : 0;
    }
    __syncthreads();
    for (int b = tid; b < NBKT; b += 256) hcnt[b] = 0;
    __syncthreads();
    for (int r = 0; r < CHNK / 256; r++) {
        int e = e0 + r * 256 + tid;
        if (e < NE) {
            int s = f ? ei[2 * e] : ei[e];
            int d = f ? ei[2 * (NE + e)] : ei[NE + e];
            int b = d >> BSH;
            int loc = atomicAdd(&hcnt[b], 1);
            int pos = hbase[b] + loc;
            if (pos < CAPB)
                staging[(size_t)b * CAPB + pos] =
                    (unsigned int)s | ((unsigned int)(d & 127) << 17);
        }
    }
}

__global__ void k_bucketscan(const int* __restrict__ gcur, int* __restrict__ bbase) {
    __shared__ int sb2[2][256];
    int t = threadIdx.x;
    int base = t * 4;
    int v0 = (base + 0 < NBKT) ? gcur[base + 0] : 0;
    int v1 = (base + 1 < NBKT) ? gcur[base + 1] : 0;
    int v2 = (base + 2 < NBKT) ? gcur[base + 2] : 0;
    int v3 = (base + 3 < NBKT) ? gcur[base + 3] : 0;
    int s0 = v0, s1 = s0 + v1, s2 = s1 + v2, s3 = s2 + v3;
    sb2[0][t] = s3;
    __syncthreads();
    int pi = 0;
    for (int off = 1; off < 256; off <<= 1) {
        int x = sb2[pi][t];
        if (t >= off) x += sb2[pi][t - off];
        sb2[pi ^ 1][t] = x;
        __syncthreads();
        pi ^= 1;
    }
    int excl = sb2[pi][t] - s3;
    if (base + 0 < NBKT) bbase[base + 0] = excl;
    if (base + 1 < NBKT) bbase[base + 1] = excl + s0;
    if (base + 2 < NBKT) bbase[base + 2] = excl + s1;
    if (base + 3 < NBKT) bbase[base + 3] = excl + s2;
}

// ---- pass 2: per-bucket build of cnt/dinv/rowptr/csr ----
__global__ __launch_bounds__(256) void k_build(const unsigned int* __restrict__ staging,
                                               const int* __restrict__ gcur,
                                               const int* __restrict__ bbase,
                                               int* __restrict__ cntg,
                                               float* __restrict__ dinv,
                                               int* __restrict__ rowptr,
                                               int* __restrict__ csr) {
    __shared__ int lcnt[128];
    __shared__ int lscan[2][128];
    __shared__ int lcur[128];
    const int tid = threadIdx.x;
    const int b = blockIdx.x;
    const int tot = min(gcur[b], CAPB);
    const int bb = bbase[b];
    const unsigned int* st = staging + (size_t)b * CAPB;
    if (tid < 128) lcnt[tid] = 0;
    __syncthreads();
    for (int i = tid; i < tot; i += 256) {
        unsigned int v = st[i];
        atomicAdd(&lcnt[v >> 17], 1);
    }
    __syncthreads();
    int pi = 0;
    if (tid < 128) lscan[0][tid] = lcnt[tid];
    __syncthreads();
    for (int off = 1; off < 128; off <<= 1) {
        if (tid < 128) {
            int x = lscan[pi][tid];
            if (tid >= off) x += lscan[pi][tid - off];
            lscan[pi ^ 1][tid] = x;
        }
        __syncthreads();
        pi ^= 1;
    }
    if (tid < 128) {
        int c = lcnt[tid];
        int excl = lscan[pi][tid] - c;
        lcur[tid] = excl;
        int node = (b << BSH) + tid;
        if (node < NN) {
            cntg[node] = c;
            dinv[node] = rsqrtf((float)(c + 1));
            rowptr[node] = bb + excl;
        }
    }
    __syncthreads();
    for (int i = tid; i < tot; i += 256) {
        unsigned int v = st[i];
        int pos = atomicAdd(&lcur[v >> 17], 1);
        csr[bb + pos] = (int)(v & 0x1ffffu);
    }
}

// ---- fused weight prep: all three matrices, fragment-contiguous hi/lo bf16 ----
// Wt[((k>>5)*MP + m)*32 + (k&31)]
__global__ void k_wprep(const float* __restrict__ W1, unsigned short* __restrict__ W1h,
                        unsigned short* __restrict__ W1l,
                        const float* __restrict__ W2, unsigned short* __restrict__ W2h,
                        unsigned short* __restrict__ W2l,
                        const float* __restrict__ W3, unsigned short* __restrict__ W3h,
                        unsigned short* __restrict__ W3l) {
    int idx = blockIdx.x * blockDim.x + threadIdx.x;
    const float* W;
    unsigned short *Wh, *Wl;
    int K, M, MP;
    if (idx < 256 * 128) {
        W = W1; Wh = W1h; Wl = W1l; K = 128; M = 256; MP = 256;
    } else if (idx < 256 * 128 + 256 * 256) {
        idx -= 256 * 128;
        W = W2; Wh = W2h; Wl = W2l; K = 256; M = 256; MP = 256;
    } else if (idx < 256 * 128 + 256 * 256 + 64 * 256) {
        idx -= 256 * 128 + 256 * 256;
        W = W3; Wh = W3h; Wl = W3l; K = 256; M = 40; MP = 64;
    } else {
        return;
    }
    int m = idx / K, k = idx - m * K;
    float v = (m < M) ? W[(size_t)k * M + m] : 0.f;
    unsigned short h, l;
    f2bf2(v, h, l);
    size_t dst = ((size_t)(k >> 5) * MP + m) * 32 + (k & 31);
    Wh[dst] = h;
    Wl[dst] = l;
}

// ---- z * dinv -> signed int8 rows + per-row scale (wave per row) ----
__global__ __launch_bounds__(256) void k_zpb8(const float* __restrict__ z,
                                              const float* __restrict__ dinv,
                                              unsigned char* __restrict__ zp8,
                                              float* __restrict__ scaleZ) {
    int wv = (blockIdx.x * blockDim.x + threadIdx.x) >> 6;
    int lane = threadIdx.x & 63;
    if (wv >= NN) return;
    float2 v = *(const float2*)(z + (size_t)wv * FIN + lane * 2);
    float d = dinv[wv];
    float a0 = v.x * d, a1 = v.y * d;
    float m = fmaxf(fabsf(a0), fabsf(a1));
#pragma unroll
    for (int off = 1; off < 64; off <<= 1) m = fmaxf(m, __shfl_xor(m, off));
    float inv = m > 0.f ? 127.f / m : 0.f;
    int q0 = (int)rintf(a0 * inv), q1 = (int)rintf(a1 * inv);
    unsigned short pk = (unsigned short)((q0 & 0xff) | ((q1 & 0xff) << 8));
    *(unsigned short*)(zp8 + (size_t)wv * FIN + lane * 2) = pk;
    if (lane == 0) scaleZ[wv] = m * (1.f / 127.f);
}

// ---- BN+ReLU+dinv -> unsigned int8 rows + per-row scale (wave per row) ----
__global__ __launch_bounds__(256) void k_bnr8(const unsigned short* __restrict__ x,
                                              const float* __restrict__ scale,
                                              const float* __restrict__ shift,
                                              const float* __restrict__ dinv,
                                              unsigned char* __restrict__ y8,
                                              float* __restrict__ scaleY) {
    int wv = (blockIdx.x * blockDim.x + threadIdx.x) >> 6;
    int lane = threadIdx.x & 63;
    if (wv >= NN) return;
    uint2 u = *(const uint2*)(x + (size_t)wv * 256 + lane * 4);
    float4 sc = *(const float4*)(scale + lane * 4);
    float4 sh = *(const float4*)(shift + lane * 4);
    float d = dinv[wv];
    float v0 = fmaxf(__uint_as_float(u.x << 16) * sc.x + sh.x, 0.f) * d;
    float v1 = fmaxf(__uint_as_float(u.x & 0xffff0000u) * sc.y + sh.y, 0.f) * d;
    float v2 = fmaxf(__uint_as_float(u.y << 16) * sc.z + sh.z, 0.f) * d;
    float v3 = fmaxf(__uint_as_float(u.y & 0xffff0000u) * sc.w + sh.w, 0.f) * d;
    float m = fmaxf(fmaxf(v0, v1), fmaxf(v2, v3));
#pragma unroll
    for (int off = 1; off < 64; off <<= 1) m = fmaxf(m, __shfl_xor(m, off));
    float inv = m > 0.f ? 255.f / m : 0.f;
    unsigned int q0 = (unsigned int)(v0 * inv + 0.5f);
    unsigned int q1 = (unsigned int)(v1 * inv + 0.5f);
    unsigned int q2 = (unsigned int)(v2 * inv + 0.5f);
    unsigned int q3 = (unsigned int)(v3 * inv + 0.5f);
    *(unsigned int*)(y8 + (size_t)wv * 256 + lane * 4) = q0 | (q1 << 8) | (q2 << 16) | (q3 << 24);
    if (lane == 0) scaleY[wv] = m * (1.f / 255.f);
}

// ---- int8 gather aggregation with cooperative csr/rscale staging ----
// F=128: signed, ushort/lane; F=256: unsigned, uint/lane.
template <int F, bool SIGNED>
__global__ __launch_bounds__(256) void k_agg8(const unsigned char* __restrict__ tab,
                                              const float* __restrict__ rscale,
                                              const float* __restrict__ dinv,
                                              const int* __restrict__ rowptr,
                                              const int* __restrict__ cnt,
                                              const int* __restrict__ csr,
                                              unsigned short* __restrict__ oa) {
    const int wid = threadIdx.x >> 6;
    const int lane = threadIdx.x & 63;
    const int wstep = (blockDim.x >> 6) * gridDim.x;
    constexpr int B = F / 64;
    const int off = lane * B;
    for (int row = blockIdx.x * (blockDim.x >> 6) + wid; row < NN; row += wstep) {
        float acc[B];
#pragma unroll
        for (int v = 0; v < B; v++) acc[v] = 0.f;
        {
            float s = rscale[row];
            if constexpr (B == 4) {
                unsigned int u = *(const unsigned int*)(tab + (size_t)row * F + off);
                acc[0] += s * ub(u, 0); acc[1] += s * ub(u, 1);
                acc[2] += s * ub(u, 2); acc[3] += s * ub(u, 3);
            } else {
                unsigned int u = *(const unsigned short*)(tab + (size_t)row * F + off);
                acc[0] += s * sbyte(u, 0); acc[1] += s * sbyte(u, 1);
            }
        }
        const int rp = rowptr[row];
        const int cn = cnt[row];
        for (int e = 0; e < cn; e += 64) {
            int rem = min(cn - e, 64);
            int myidx = 0;
            float mys = 0.f;
            if (lane < rem) {
                myidx = csr[rp + e + lane];
                mys = rscale[myidx];
            }
            int q = 0;
            for (; q + 8 <= rem; q += 8) {
                int idx[8];
                float s[8];
                unsigned int u[8];
#pragma unroll
                for (int j = 0; j < 8; j++) {
                    idx[j] = __shfl(myidx, q + j);
                    s[j] = __shfl(mys, q + j);
                }
#pragma unroll
                for (int j = 0; j < 8; j++) {
                    if constexpr (B == 4)
                        u[j] = *(const unsigned int*)(tab + (size_t)idx[j] * F + off);
                    else
                        u[j] = *(const unsigned short*)(tab + (size_t)idx[j] * F + off);
                }
#pragma unroll
                for (int j = 0; j < 8; j++) {
                    if constexpr (B == 4) {
                        acc[0] += s[j] * ub(u[j], 0); acc[1] += s[j] * ub(u[j], 1);
                        acc[2] += s[j] * ub(u[j], 2); acc[3] += s[j] * ub(u[j], 3);
                    } else {
                        acc[0] += s[j] * sbyte(u[j], 0); acc[1] += s[j] * sbyte(u[j], 1);
                    }
                }
            }
            for (; q < rem; q++) {
                int idx = __shfl(myidx, q);
                float s = __shfl(mys, q);
                if constexpr (B == 4) {
                    unsigned int u = *(const unsigned int*)(tab + (size_t)idx * F + off);
                    acc[0] += s * ub(u, 0); acc[1] += s * ub(u, 1);
                    acc[2] += s * ub(u, 2); acc[3] += s * ub(u, 3);
                } else {
                    unsigned int u = *(const unsigned short*)(tab + (size_t)idx * F + off);
                    acc[0] += s * sbyte(u, 0); acc[1] += s * sbyte(u, 1);
                }
            }
        }
        float d = dinv[row];
        size_t p = (size_t)row * F + off;
        if constexpr (B == 4) {
            uint2 o;
            o.x = (unsigned int)f2bf(acc[0] * d) | ((unsigned int)f2bf(acc[1] * d) << 16);
            o.y = (unsigned int)f2bf(acc[2] * d) | ((unsigned int)f2bf(acc[3] * d) << 16);
            *(uint2*)(oa + p) = o;
        } else {
            *(unsigned int*)(oa + p) =
                (unsigned int)f2bf(acc[0] * d) | ((unsigned int)f2bf(acc[1] * d) << 16);
        }
    }
}

// ---- GEMM: 64-row x 128-col tile; A bf16, W hi/lo; bias + BN stats fused ----
template <int K>
__global__ __launch_bounds__(256) void k_gemm(const unsigned short* __restrict__ A,
                                              const unsigned short* __restrict__ Wth,
                                              const unsigned short* __restrict__ Wtl,
                                              const float* __restrict__ bias,
                                              unsigned short* __restrict__ outX,
                                              float* __restrict__ s1,
                                              float* __restrict__ s2) {
    __shared__ unsigned short sA[64][40];
    const int t = threadIdx.x;
    const int w = t >> 6, lane = t & 63;
    const int quad = lane >> 4, l16 = lane & 15;
    const int rowBase = blockIdx.y * 64;
    const int colW = blockIdx.x * 128 + w * 32;
    f32x4 acc[4][2];
#pragma unroll
    for (int i = 0; i < 4; i++)
#pragma unroll
        for (int j = 0; j < 2; j++) acc[i][j] = (f32x4)0.f;

    for (int k0 = 0; k0 < K; k0 += 32) {
        int gr = rowBase + (t >> 2);
        int4 v = {0, 0, 0, 0};
        if (gr < NN) v = *(const int4*)(A + (size_t)gr * K + k0 + (t & 3) * 8);
        __syncthreads();
        *(int4*)&sA[t >> 2][(t & 3) * 8] = v;
        __syncthreads();
        const int kb = k0 >> 5;
        bf8 bh[2], bl[2];
#pragma unroll
        for (int j = 0; j < 2; j++) {
            size_t bo = ((size_t)(kb * 256 + colW + j * 16 + l16)) * 32 + quad * 8;
            bh[j] = *(const bf8*)(Wth + bo);
            bl[j] = *(const bf8*)(Wtl + bo);
        }
#pragma unroll
        for (int i = 0; i < 4; i++) {
            bf8 a = *(const bf8*)&sA[i * 16 + l16][quad * 8];
#pragma unroll
            for (int j = 0; j < 2; j++) {
                acc[i][j] = __builtin_amdgcn_mfma_f32_16x16x32_bf16(a, bh[j], acc[i][j], 0, 0, 0);
                acc[i][j] = __builtin_amdgcn_mfma_f32_16x16x32_bf16(a, bl[j], acc[i][j], 0, 0, 0);
            }
        }
    }
#pragma unroll
    for (int j = 0; j < 2; j++) {
        int col = colW + j * 16 + l16;
        float b = bias[col];
        float s1p = 0.f, s2p = 0.f;
#pragma unroll
        for (int i = 0; i < 4; i++) {
#pragma unroll
            for (int r = 0; r < 4; r++) {
                int row = rowBase + i * 16 + quad * 4 + r;
                if (row < NN) {
                    float v = acc[i][j][r] + b;
                    s1p += v;
                    s2p += v * v;
                    outX[(size_t)row * 256 + col] = f2bf(v);
                }
            }
        }
        s1p += __shfl_xor(s1p, 16); s1p += __shfl_xor(s1p, 32);
        s2p += __shfl_xor(s2p, 16); s2p += __shfl_xor(s2p, 32);
        if (quad == 0) {
            atomicAdd(&s1[col], s1p);
            atomicAdd(&s2[col], s2p);
        }
    }
}

// ---- layer-3 GEMM -> signed int8 H3 (64-col pad) + per-row scale ----
__global__ __launch_bounds__(256) void k_mgemm3(const unsigned short* __restrict__ y2,
                                                const unsigned short* __restrict__ Wth,
                                                const unsigned short* __restrict__ Wtl,
                                                unsigned char* __restrict__ H8,
                                                float* __restrict__ scaleH) {
    __shared__ unsigned short sA[128][40];
    __shared__ float sM[128][4];
    const int t = threadIdx.x;
    const int w = t >> 6, lane = t & 63;
    const int quad = lane >> 4, l16 = lane & 15;
    const int rowBase = blockIdx.x << 7;
    f32x4 acc[8];
#pragma unroll
    for (int i = 0; i < 8; i++) acc[i] = (f32x4)0.f;

    for (int k0 = 0; k0 < 256; k0 += 32) {
        const int kb = k0 >> 5;
        int id0 = t, id1 = t + 256;
        int gr0 = rowBase + (id0 >> 2), gr1 = rowBase + (id1 >> 2);
        int4 zz = {0, 0, 0, 0};
        int4 v0 = (gr0 < NN) ? *(const int4*)(y2 + (size_t)gr0 * 256 + k0 + (id0 & 3) * 8) : zz;
        int4 v1 = (gr1 < NN) ? *(const int4*)(y2 + (size_t)gr1 * 256 + k0 + (id1 & 3) * 8) : zz;
        __syncthreads();
        *(int4*)&sA[id0 >> 2][(id0 & 3) * 8] = v0;
        *(int4*)&sA[id1 >> 2][(id1 & 3) * 8] = v1;
        __syncthreads();
        size_t bo = ((size_t)(kb * 64 + w * 16 + l16)) * 32 + quad * 8;
        bf8 bh = *(const bf8*)(Wth + bo);
        bf8 bl = *(const bf8*)(Wtl + bo);
#pragma unroll
        for (int i = 0; i < 8; i++) {
            bf8 a = *(const bf8*)&sA[i * 16 + l16][quad * 8];
            acc[i] = __builtin_amdgcn_mfma_f32_16x16x32_bf16(a, bh, acc[i], 0, 0, 0);
            acc[i] = __builtin_amdgcn_mfma_f32_16x16x32_bf16(a, bl, acc[i], 0, 0, 0);
        }
    }
#pragma unroll
    for (int i = 0; i < 8; i++) {
#pragma unroll
        for (int r = 0; r < 4; r++) {
            float m = fabsf(acc[i][r]);
            m = fmaxf(m, __shfl_xor(m, 1));
            m = fmaxf(m, __shfl_xor(m, 2));
            m = fmaxf(m, __shfl_xor(m, 4));
            m = fmaxf(m, __shfl_xor(m, 8));
            if (l16 == 0) sM[i * 16 + quad * 4 + r][w] = m;
        }
    }
    __syncthreads();
    const int col = w * 16 + l16;
#pragma unroll
    for (int i = 0; i < 8; i++) {
#pragma unroll
        for (int r = 0; r < 4; r++) {
            int rloc = i * 16 + quad * 4 + r;
            int row = rowBase + rloc;
            float m = fmaxf(fmaxf(sM[rloc][0], sM[rloc][1]), fmaxf(sM[rloc][2], sM[rloc][3]));
            float inv = m > 0.f ? 127.f / m : 0.f;
            if (row < NN) {
                int q = (int)rintf(acc[i][r] * inv);
                H8[(size_t)row * 64 + col] = (unsigned char)(q & 0xff);
                if (w == 0 && l16 == 0) scaleH[row] = m * (1.f / 127.f);
            }
        }
    }
}

// ---- final aggregation from int8 H8 (64B rows), cooperative staging ----
__global__ __launch_bounds__(256) void k_aggfb8(const unsigned char* __restrict__ tab,
                                                const float* __restrict__ rscale,
                                                const float* __restrict__ dinv,
                                                const int* __restrict__ rowptr,
                                                const int* __restrict__ cnt,
                                                const int* __restrict__ csr,
                                                const float* __restrict__ bias,
                                                float* __restrict__ out) {
    const int wid = threadIdx.x >> 6;
    const int lane = threadIdx.x & 63;
    const int wstep = (blockDim.x >> 6) * gridDim.x;
    for (int row = blockIdx.x * (blockDim.x >> 6) + wid; row < NN; row += wstep) {
        float acc = rscale[row] * (float)(int)(signed char)tab[(size_t)row * 64 + lane];
        const int rp = rowptr[row];
        const int cn = cnt[row];
        for (int e = 0; e < cn; e += 64) {
            int rem = min(cn - e, 64);
            int myidx = 0;
            float mys = 0.f;
            if (lane < rem) {
                myidx = csr[rp + e + lane];
                mys = rscale[myidx];
            }
            int q = 0;
            for (; q + 8 <= rem; q += 8) {
                int idx[8];
                float s[8];
                float v[8];
#pragma unroll
                for (int j = 0; j < 8; j++) {
                    idx[j] = __shfl(myidx, q + j);
                    s[j] = __shfl(mys, q + j);
                }
#pragma unroll
                for (int j = 0; j < 8; j++)
                    v[j] = (float)(int)(signed char)tab[(size_t)idx[j] * 64 + lane];
#pragma unroll
                for (int j = 0; j < 8; j++) acc += s[j] * v[j];
            }
            for (; q < rem; q++) {
                int idx = __shfl(myidx, q);
                float s = __shfl(mys, q);
                acc += s * (float)(int)(signed char)tab[(size_t)idx * 64 + lane];
            }
        }
        if (lane < FOUT) out[(size_t)row * FOUT + lane] = acc * dinv[row] + bias[lane];
    }
}

__global__ void k_bnfold(const float* __restrict__ s1, const float* __restrict__ s2,
                         const float* __restrict__ g, const float* __restrict__ be,
                         float* __restrict__ scale, float* __restrict__ shift) {
    int c = threadIdx.x;
    if (c < 256) {
        float mean = s1[c] * (1.f / NN);
        float var = s2[c] * (1.f / NN) - mean * mean;
        float sc = g[c] * rsqrtf(var + EPSV);
        scale[c] = sc;
        shift[c] = be[c] - mean * sc;
    }
}

// ---- BN+ReLU bf16->bf16 table (x dinv) — layer-2 output for mgemm3 ----
__global__ void k_bnr(const unsigned short* __restrict__ x,
                      const float* __restrict__ scale, const float* __restrict__ shift,
                      const float* __restrict__ dinv, unsigned short* __restrict__ oy) {
    int i = blockIdx.x * blockDim.x + threadIdx.x;
    if (i >= NN * 128) return;
    int row = i >> 7;
    int c = (i & 127) * 2;
    unsigned int u = ((const unsigned int*)x)[i];
    float x0 = __uint_as_float(u << 16);
    float x1 = __uint_as_float(u & 0xffff0000u);
    float d = dinv[row];
    float v0 = fmaxf(x0 * scale[c + 0] + shift[c + 0], 0.f) * d;
    float v1 = fmaxf(x1 * scale[c + 1] + shift[c + 1], 0.f) * d;
    ((unsigned int*)oy)[i] = (unsigned int)f2bf(v0) | ((unsigned int)f2bf(v1) << 16);
}

extern "C" void kernel_launch(void* const* d_in, const int* in_sizes, int n_in,
                              void* d_out, int out_size, void* d_ws, size_t ws_size,
                              hipStream_t stream) {
    const int* ei = (const int*)d_in[0];
    const float* z = (const float*)d_in[1];
    const float* W1 = (const float*)d_in[2];
    const float* b1 = (const float*)d_in[3];
    const float* g1 = (const float*)d_in[4];
    const float* be1 = (const float*)d_in[5];
    const float* W2 = (const float*)d_in[6];
    const float* b2 = (const float*)d_in[7];
    const float* g2 = (const float*)d_in[8];
    const float* be2 = (const float*)d_in[9];
    const float* W3 = (const float*)d_in[10];
    const float* b3 = (const float*)d_in[11];
    float* out = (float*)d_out;

    char* w = (char*)d_ws;
    size_t o = 0;
    auto take = [&](size_t bytes) {
        char* p = w + o;
        o = (o + bytes + 255) & ~(size_t)255;
        return p;
    };
    int* cnt = (int*)take((size_t)NN * 4);
    int* rowptr = (int*)take((size_t)NN * 4);
    int* gcur = (int*)take(NBKT * 4);
    int* bbase = (int*)take(NBKT * 4);
    int* csr = (int*)take((size_t)NE * 4);
    unsigned int* staging = (unsigned int*)take((size_t)NBKT * CAPB * 4);
    float* dinv = (float*)take((size_t)NN * 4);
    float* stat = (float*)take(4 * 256 * 4);
    float* sc1 = (float*)take(256 * 4);
    float* sh1 = (float*)take(256 * 4);
    float* sc2 = (float*)take(256 * 4);
    float* sh2 = (float*)take(256 * 4);
    unsigned short* Wt1h = (unsigned short*)take(256 * 128 * 2);
    unsigned short* Wt1l = (unsigned short*)take(256 * 128 * 2);
    unsigned short* Wt2h = (unsigned short*)take(256 * 256 * 2);
    unsigned short* Wt2l = (unsigned short*)take(256 * 256 * 2);
    unsigned short* Wt3h = (unsigned short*)take(64 * 256 * 2);
    unsigned short* Wt3l = (unsigned short*)take(64 * 256 * 2);
    unsigned char* zp8 = (unsigned char*)take((size_t)NN * FIN);
    unsigned char* y1_8 = (unsigned char*)take((size_t)NN * FH);
    unsigned char* H8 = (unsigned char*)take((size_t)NN * 64);
    float* scaleZ = (float*)take((size_t)NN * 4);
    float* scaleY = (float*)take((size_t)NN * 4);
    float* scaleH = (float*)take((size_t)NN * 4);
    unsigned short* P1 = (unsigned short*)take((size_t)NN * 256 * 2);
    unsigned short* P2 = (unsigned short*)take((size_t)NN * 512 * 2);

    unsigned short* a1 = P1;
    unsigned short* x1 = P2;
    unsigned short* a2 = P2 + (size_t)NN * 256;
    unsigned short* x2 = P1;
    unsigned short* y2 = P2;
    float* s1a = stat, *s2a = stat + 256, *s1b = stat + 512, *s2b = stat + 768;

    hipMemsetAsync(gcur, 0, NBKT * 4, stream);
    hipMemsetAsync(stat, 0, 4 * 256 * 4, stream);

    // CSR build (two-level counting sort; dtype flag computed inline)
    k_bin<<<(NE + CHNK - 1) / CHNK, 256, 0, stream>>>(ei, gcur, staging);
    k_bucketscan<<<1, 256, 0, stream>>>(gcur, bbase);
    k_build<<<NBKT, 256, 0, stream>>>(staging, gcur, bbase, cnt, dinv, rowptr, csr);

    k_wprep<<<(256 * 128 + 256 * 256 + 64 * 256 + 255) / 256, 256, 0, stream>>>(
        W1, Wt1h, Wt1l, W2, Wt2h, Wt2l, W3, Wt3h, Wt3l);

    const int GR = (NN + 63) / 64;
    const int WV = (NN + 3) / 4;

    // layer 1
    k_zpb8<<<WV, 256, 0, stream>>>(z, dinv, zp8, scaleZ);
    k_agg8<128, true><<<2560, 256, 0, stream>>>(zp8, scaleZ, dinv, rowptr, cnt, csr, a1);
    k_gemm<128><<<dim3(2, GR), 256, 0, stream>>>(a1, Wt1h, Wt1l, b1, x1, s1a, s2a);
    k_bnfold<<<1, 256, 0, stream>>>(s1a, s2a, g1, be1, sc1, sh1);
    k_bnr8<<<WV, 256, 0, stream>>>(x1, sc1, sh1, dinv, y1_8, scaleY);

    // layer 2
    k_agg8<256, false><<<2560, 256, 0, stream>>>(y1_8, scaleY, dinv, rowptr, cnt, csr, a2);
    k_gemm<256><<<dim3(2, GR), 256, 0, stream>>>(a2, Wt2h, Wt2l, b2, x2, s1b, s2b);
    k_bnfold<<<1, 256, 0, stream>>>(s1b, s2b, g2, be2, sc2, sh2);
    k_bnr<<<(NN * 128 + 255) / 256, 256, 0, stream>>>(x2, sc2, sh2, dinv, y2);

    // layer 3
    k_mgemm3<<<NBKT, 256, 0, stream>>>(y2, Wt3h, Wt3l, H8, scaleH);
    k_aggfb8<<<2560, 256, 0, stream>>>(H8, scaleH, dinv, rowptr, cnt, csr, b3, out);
}